// Round 5
// baseline (264.773 us; speedup 1.0000x reference)
//
#include <hip/hip_runtime.h>
#include <hip/hip_bf16.h>

typedef __attribute__((ext_vector_type(8))) short bf16x8;
typedef __attribute__((ext_vector_type(4))) float f32x4;
typedef __attribute__((ext_vector_type(4))) unsigned short u16x4;
typedef unsigned short US;

__device__ __forceinline__ f32x4 mfma16(bf16x8 a, bf16x8 b, f32x4 c) {
  return __builtin_amdgcn_mfma_f32_16x16x32_bf16(a, b, c, 0, 0, 0);
}

__device__ __forceinline__ US f2bf(float f) {
  union { float f; unsigned u; } x; x.f = f;
  unsigned r = x.u + 0x7fffu + ((x.u >> 16) & 1u);
  return (US)(r >> 16);
}

// async global->LDS, 16B per lane; LDS dest = wave-uniform base + lane*16
__device__ __forceinline__ void gld16(const US* gp, US* lp) {
  __builtin_amdgcn_global_load_lds(
      (const __attribute__((address_space(1))) unsigned*)gp,
      (__attribute__((address_space(3))) unsigned*)lp, 16, 0, 0);
}

// row remap fusing the time-concat: mode1: r=b*768+s -> b*1024+s ; mode2: r=b*256+s -> b*1024+768+s
__device__ __forceinline__ int map_row(int r, int mode) {
  if (mode == 1) { int b = r / 768; return b * 1024 + (r - b * 768); }
  if (mode == 2) { int b = r >> 8; return b * 1024 + 768 + (r & 255); }
  return r;
}

// ----------------- fp32 -> bf16 cast -----------------
__global__ void k_cast(const float* __restrict__ src, US* __restrict__ dst, int n4) {
  int i = blockIdx.x * 256 + threadIdx.x;
  if (i >= n4) return;
  f32x4 v = *reinterpret_cast<const f32x4*>(src + (size_t)i * 4);
  u16x4 o;
  o[0] = f2bf(v[0]); o[1] = f2bf(v[1]); o[2] = f2bf(v[2]); o[3] = f2bf(v[3]);
  *reinterpret_cast<u16x4*>(dst + (size_t)i * 4) = o;
}

// ------- batched transpose-pack: fp32 src[R][C] -> bf16 dst[C][R] -------
__global__ __launch_bounds__(256)
void k_tpack(const float* __restrict__ src, US* __restrict__ dst,
             int R, int C, long sbs, long dbs) {
  __shared__ float tile[32][33];
  int c0 = blockIdx.x * 32, r0 = blockIdx.y * 32;
  src += (long)blockIdx.z * sbs;
  dst += (long)blockIdx.z * dbs;
  int tx = threadIdx.x, ty = threadIdx.y;
#pragma unroll
  for (int i = 0; i < 4; ++i)
    tile[ty + 8 * i][tx] = src[(size_t)(r0 + ty + 8 * i) * C + c0 + tx];
  __syncthreads();
#pragma unroll
  for (int i = 0; i < 4; ++i)
    dst[(size_t)(c0 + ty + 8 * i) * R + r0 + tx] = f2bf(tile[tx][ty + 8 * i]);
}

// ------- fused QKV projection GEMM: A[M,K] x BT[2560,K]^T -> q_raw / kv_raw -------
// double-buffered LDS with prefetch-before-compute (1 barrier/K-step)
template <int CMAP>
__global__ __launch_bounds__(256, 2)
void k_gemm_qkv(const US* __restrict__ A, const US* __restrict__ BT,
                float* __restrict__ Cq, float* __restrict__ Ckv,
                int M, int K) {
  __shared__ __align__(16) US lA[2][128 * 32];
  __shared__ __align__(16) US lB[2][128 * 32];
  const int tid = threadIdx.x;
  const int lane = tid & 63;
  const int wid = tid >> 6;
  const int wm = wid >> 1, wn = wid & 1;
  const int m0 = blockIdx.y * 128, n0 = blockIdx.x * 128;
  const int g = lane >> 4, c = lane & 15;
  const int lrow = lane >> 2, lcol = (lane & 3) * 8;
  const size_t ga0 = (size_t)(m0 + wid * 16 + lrow) * K + lcol;
  const size_t ga1 = (size_t)(m0 + 64 + wid * 16 + lrow) * K + lcol;
  const size_t gb0 = (size_t)(n0 + wid * 16 + lrow) * K + lcol;
  const size_t gb1 = (size_t)(n0 + 64 + wid * 16 + lrow) * K + lcol;

  auto stage = [&](int bi, int k0) {
    gld16(A + ga0 + k0, &lA[bi][(wid * 16) * 32]);
    gld16(A + ga1 + k0, &lA[bi][(64 + wid * 16) * 32]);
    gld16(BT + gb0 + k0, &lB[bi][(wid * 16) * 32]);
    gld16(BT + gb1 + k0, &lB[bi][(64 + wid * 16) * 32]);
  };

  f32x4 acc[4][4];
#pragma unroll
  for (int i = 0; i < 4; ++i)
#pragma unroll
    for (int j = 0; j < 4; ++j) acc[i][j] = f32x4{0.f, 0.f, 0.f, 0.f};

  const int nt = K >> 5;
  stage(0, 0);
  __syncthreads();
  for (int t = 0; t < nt; ++t) {
    const int bi = t & 1;
    if (t + 1 < nt) stage(bi ^ 1, (t + 1) * 32);
    bf16x8 af[4], bfr[4];
#pragma unroll
    for (int i = 0; i < 4; ++i) {
      af[i] = *reinterpret_cast<const bf16x8*>(&lA[bi][(wm * 64 + i * 16 + c) * 32 + g * 8]);
      bfr[i] = *reinterpret_cast<const bf16x8*>(&lB[bi][(wn * 64 + i * 16 + c) * 32 + g * 8]);
    }
#pragma unroll
    for (int i = 0; i < 4; ++i)
#pragma unroll
      for (int j = 0; j < 4; ++j)
        acc[i][j] = mfma16(af[i], bfr[j], acc[i][j]);
    __syncthreads();  // drains vmcnt(0): prefetch landed; buf[bi] reads done
  }

  const bool isq = (n0 < 2048);
  float* Cb = isq ? Cq : Ckv;
  const int Nst = isq ? 2048 : 512;
  const int nb = (isq ? n0 : n0 - 2048) + wn * 64 + c;
#pragma unroll
  for (int i = 0; i < 4; ++i) {
#pragma unroll
    for (int r = 0; r < 4; ++r) {
      int orow = map_row(m0 + wm * 64 + i * 16 + 4 * g + r, CMAP);
      float* cp = Cb + (size_t)orow * Nst + nb;
#pragma unroll
      for (int j = 0; j < 4; ++j) cp[j * 16] = acc[i][j][r];
    }
  }
}

// ------- fused output GEMM: enc[4096,2048] -> out0 (rows s<768) / out1 (rows s>=768) -------
__global__ __launch_bounds__(256, 2)
void k_gemm_out(const US* __restrict__ A, const US* __restrict__ BT0, const US* __restrict__ BT1,
                float* __restrict__ C0, float* __restrict__ C1) {
  const int m0 = blockIdx.y * 128, n0 = blockIdx.x * 128;
  const int s0 = m0 & 1023;
  const bool is0 = (s0 < 768);
  if (!is0 && n0 >= 1024) return;
  const US* __restrict__ BT = is0 ? BT0 : BT1;
  const int K = 2048;
  __shared__ __align__(16) US lA[2][128 * 32];
  __shared__ __align__(16) US lB[2][128 * 32];
  const int tid = threadIdx.x;
  const int lane = tid & 63;
  const int wid = tid >> 6;
  const int wm = wid >> 1, wn = wid & 1;
  const int g = lane >> 4, c = lane & 15;
  const int lrow = lane >> 2, lcol = (lane & 3) * 8;
  const size_t ga0 = (size_t)(m0 + wid * 16 + lrow) * K + lcol;
  const size_t ga1 = (size_t)(m0 + 64 + wid * 16 + lrow) * K + lcol;
  const size_t gb0 = (size_t)(n0 + wid * 16 + lrow) * K + lcol;
  const size_t gb1 = (size_t)(n0 + 64 + wid * 16 + lrow) * K + lcol;

  auto stage = [&](int bi, int k0) {
    gld16(A + ga0 + k0, &lA[bi][(wid * 16) * 32]);
    gld16(A + ga1 + k0, &lA[bi][(64 + wid * 16) * 32]);
    gld16(BT + gb0 + k0, &lB[bi][(wid * 16) * 32]);
    gld16(BT + gb1 + k0, &lB[bi][(64 + wid * 16) * 32]);
  };

  f32x4 acc[4][4];
#pragma unroll
  for (int i = 0; i < 4; ++i)
#pragma unroll
    for (int j = 0; j < 4; ++j) acc[i][j] = f32x4{0.f, 0.f, 0.f, 0.f};

  const int nt = K >> 5;
  stage(0, 0);
  __syncthreads();
  for (int t = 0; t < nt; ++t) {
    const int bi = t & 1;
    if (t + 1 < nt) stage(bi ^ 1, (t + 1) * 32);
    bf16x8 af[4], bfr[4];
#pragma unroll
    for (int i = 0; i < 4; ++i) {
      af[i] = *reinterpret_cast<const bf16x8*>(&lA[bi][(wm * 64 + i * 16 + c) * 32 + g * 8]);
      bfr[i] = *reinterpret_cast<const bf16x8*>(&lB[bi][(wn * 64 + i * 16 + c) * 32 + g * 8]);
    }
#pragma unroll
    for (int i = 0; i < 4; ++i)
#pragma unroll
      for (int j = 0; j < 4; ++j)
        acc[i][j] = mfma16(af[i], bfr[j], acc[i][j]);
    __syncthreads();
  }

  const int col = n0 + wn * 64 + c;
#pragma unroll
  for (int i = 0; i < 4; ++i) {
#pragma unroll
    for (int r = 0; r < 4; ++r) {
      const int rf = m0 + wm * 64 + i * 16 + 4 * g + r;
      const int b = rf >> 10, s = rf & 1023;
      float* cp = is0 ? (C0 + (size_t)(b * 768 + s) * 2048 + col)
                      : (C1 + (size_t)(b * 256 + s - 768) * 1024 + col);
#pragma unroll
      for (int j = 0; j < 4; ++j) cp[j * 16] = acc[i][j][r];
    }
  }
}

// ------- RoPE: q_raw(f32)->q_bf (roped*scale), kv_raw k-part -> k_bf + k_out(f32) -------
__global__ __launch_bounds__(256)
void k_rope(const float* __restrict__ q_raw, const float* __restrict__ kv_raw,
            const int* __restrict__ pos, US* __restrict__ q_bf,
            US* __restrict__ k_bf, float* __restrict__ k_out) {
  __shared__ float sa[128], ca[128];
  const int bt = blockIdx.x;
  const int tid = threadIdx.x;
  const int p = pos[bt];
  if (tid < 128) {
    float inv_ts = powf(10000.0f, -(float)tid * (1.0f / 128.0f));
    float r = (float)p * inv_ts;
    sa[tid] = sinf(r);
    ca[tid] = cosf(r);
  }
  __syncthreads();
  const float scale = 0.0625f;  // 256^-0.5
  const size_t qo = (size_t)bt * 2048;
#pragma unroll
  for (int it = 0; it < 4; ++it) {
    int idx = it * 256 + tid;
    int n = idx >> 7, j = idx & 127;
    float x1 = q_raw[qo + n * 256 + j];
    float x2 = q_raw[qo + n * 256 + j + 128];
    float s = sa[j], co = ca[j];
    q_bf[qo + n * 256 + j] = f2bf(scale * (x1 * co - x2 * s));
    q_bf[qo + n * 256 + j + 128] = f2bf(scale * (x2 * co + x1 * s));
  }
  if (tid < 128) {
    int j = tid;
    const size_t ko = (size_t)bt * 512;
    float x1 = kv_raw[ko + j], x2 = kv_raw[ko + j + 128];
    float s = sa[j], co = ca[j];
    float o1 = x1 * co - x2 * s, o2 = x2 * co + x1 * s;
    const size_t kd = (size_t)bt * 256;
    k_bf[kd + j] = f2bf(o1);
    k_bf[kd + j + 128] = f2bf(o2);
    k_out[kd + j] = o1;
    k_out[kd + j + 128] = o2;
  }
}

// ------- V: kv_raw v-part -> v_out(f32) + vt bf16 [b][h][t] -------
__global__ __launch_bounds__(256)
void k_vtrans(const float* __restrict__ kv_raw, float* __restrict__ v_out, US* __restrict__ vt) {
  __shared__ float tile[32][33];
  int t0 = blockIdx.x * 32, h0 = blockIdx.y * 32, b = blockIdx.z;
  int tx = threadIdx.x, ty = threadIdx.y;
#pragma unroll
  for (int i = 0; i < 4; ++i) {
    int t = t0 + ty + 8 * i;
    float v = kv_raw[(size_t)(b * 1024 + t) * 512 + 256 + h0 + tx];
    tile[ty + 8 * i][tx] = v;
    v_out[(size_t)(b * 1024 + t) * 256 + h0 + tx] = v;
  }
  __syncthreads();
#pragma unroll
  for (int i = 0; i < 4; ++i) {
    int h = h0 + ty + 8 * i;
    vt[(size_t)(b * 256 + h) * 1024 + t0 + tx] = f2bf(tile[tx][ty + 8 * i]);
  }
}

// ------- flash attention: 1024 blocks x 128 threads (2 waves = 2 heads) -------
// K chunk in LDS (double-buffered, XOR-swizzled both-sides); V read directly
// from global (L2-resident, 16KB/chunk shared by all heads). Blocks ordered
// long-qt-first; 4 blocks/CU resident drain dynamically (LPT, no mapping
// assumptions). QK chain split 8->4+4 to shorten the dependent-MFMA path.
__global__ __launch_bounds__(128, 2)
void k_attn(const US* __restrict__ qb, const US* __restrict__ kb,
            const US* __restrict__ vt, US* __restrict__ enc) {
  __shared__ __align__(16) US lK[2][32 * 256];   // 16KB x2
  const int id = blockIdx.x;
  const int qt = 63 - (id >> 4);    // long blocks dispatch first (LPT)
  const int hg = (id >> 2) & 3;
  const int b = id & 3;
  const int tid = threadIdx.x;
  const int wid = tid >> 6;
  const int lane = tid & 63;
  const int g = lane >> 4, c = lane & 15;
  const int qbase = qt * 16;
  const int n = hg * 2 + wid;

  const US* kbB = kb + (size_t)b * 262144;
  const US* vtB = vt + (size_t)b * 262144;

  bf16x8 qf[8];
  {
    const US* qp = qb + ((size_t)((b * 1024 + qbase + c) * 8 + n)) * 256 + 8 * g;
#pragma unroll
    for (int ch = 0; ch < 8; ++ch)
      qf[ch] = *reinterpret_cast<const bf16x8*>(qp + ch * 32);
  }

  // stage K chunk [c0..c0+31]: granule (r,s) holds global col-granule s^(r&7)
  auto stage = [&](int bi, int c0) {
#pragma unroll
    for (int j = 0; j < 8; ++j) {
      const int rbase = wid * 16 + j * 2;
      const int rk = rbase + (lane >> 5);
      const int sk = lane & 31;
      gld16(kbB + (size_t)(c0 + rk) * 256 + (sk ^ (rk & 7)) * 8,
            &lK[bi][rbase * 256]);
    }
  };

  f32x4 acc[16];
#pragma unroll
  for (int i = 0; i < 16; ++i) acc[i] = f32x4{0.f, 0.f, 0.f, 0.f};
  float m_run = -3.0e38f, l_run = 0.f;

  const int nC = qbase / 32 + 1;
  stage(0, 0);
  __syncthreads();

  for (int i = 0; i < nC; ++i) {
    const int c0 = 32 * i;
    const int bi = i & 1;
    if (i + 1 < nC) stage(bi ^ 1, c0 + 32);

    const bool hb = (c0 + 16 <= qbase);
    // QK: two parallel 4-chains, summed (halves dependent-MFMA latency chain)
    f32x4 sA0 = {0.f, 0.f, 0.f, 0.f}, sA1 = {0.f, 0.f, 0.f, 0.f};
    f32x4 sB0 = {0.f, 0.f, 0.f, 0.f}, sB1 = {0.f, 0.f, 0.f, 0.f};
#pragma unroll
    for (int ch = 0; ch < 4; ++ch) {
      const int s0_ = (((2 * ch) * 4 + g) ^ (c & 7)) * 8;
      const int s1_ = (((2 * ch + 1) * 4 + g) ^ (c & 7)) * 8;
      sA0 = mfma16(*reinterpret_cast<const bf16x8*>(&lK[bi][c * 256 + s0_]), qf[2 * ch], sA0);
      sA1 = mfma16(*reinterpret_cast<const bf16x8*>(&lK[bi][c * 256 + s1_]), qf[2 * ch + 1], sA1);
    }
    if (hb) {
#pragma unroll
      for (int ch = 0; ch < 4; ++ch) {
        const int s0_ = (((2 * ch) * 4 + g) ^ (c & 7)) * 8;
        const int s1_ = (((2 * ch + 1) * 4 + g) ^ (c & 7)) * 8;
        sB0 = mfma16(*reinterpret_cast<const bf16x8*>(&lK[bi][(c + 16) * 256 + s0_]), qf[2 * ch], sB0);
        sB1 = mfma16(*reinterpret_cast<const bf16x8*>(&lK[bi][(c + 16) * 256 + s1_]), qf[2 * ch + 1], sB1);
      }
    }
    f32x4 sA, sB;
#pragma unroll
    for (int r = 0; r < 4; ++r) { sA[r] = sA0[r] + sA1[r]; sB[r] = sB0[r] + sB1[r]; }
    if (c0 == qbase) {
#pragma unroll
      for (int r = 0; r < 4; ++r)
        if (4 * g + r > c) sA[r] = -3.0e38f;
    }
    if (hb && (c0 + 16 == qbase)) {
#pragma unroll
      for (int r = 0; r < 4; ++r)
        if (4 * g + r > c) sB[r] = -3.0e38f;
    }
    float tm = fmaxf(fmaxf(sA[0], sA[1]), fmaxf(sA[2], sA[3]));
    if (hb) tm = fmaxf(tm, fmaxf(fmaxf(sB[0], sB[1]), fmaxf(sB[2], sB[3])));
    tm = fmaxf(tm, __shfl_xor(tm, 16));
    tm = fmaxf(tm, __shfl_xor(tm, 32));
    // defer-max: only rescale when the running max actually grows past THR
    if (!__all(tm - m_run <= 8.0f)) {
      const float m_new = fmaxf(m_run, tm);
      const float alpha = __expf(m_run - m_new);
      float aacc[4];
#pragma unroll
      for (int r = 0; r < 4; ++r) aacc[r] = __shfl(alpha, 4 * g + r);
#pragma unroll
      for (int ht = 0; ht < 16; ++ht) {
        acc[ht][0] *= aacc[0]; acc[ht][1] *= aacc[1];
        acc[ht][2] *= aacc[2]; acc[ht][3] *= aacc[3];
      }
      l_run *= alpha;
      m_run = m_new;
    }
    float pA[4], pB[4];
    float ls = 0.f;
#pragma unroll
    for (int r = 0; r < 4; ++r) { pA[r] = __expf(sA[r] - m_run); ls += pA[r]; }
#pragma unroll
    for (int r = 0; r < 4; ++r) { pB[r] = hb ? __expf(sB[r] - m_run) : 0.f; ls += pB[r]; }
    ls += __shfl_xor(ls, 16);
    ls += __shfl_xor(ls, 32);
    l_run += ls;
    // redistribute P^T (D-layout) into PV A-fragment layout
    bf16x8 paf;
#pragma unroll
    for (int j = 0; j < 8; ++j) {
      const int srcl = ((2 * (g & 1) + (j >> 2)) << 4) + c;
      float va = __shfl(pA[j & 3], srcl);
      float vb = __shfl(pB[j & 3], srcl);
      float pv = (g < 2) ? va : vb;
      paf[j] = (short)f2bf(pv);
    }
    // PV: V direct from global (L2-resident, shared across heads)
    const US* vb2 = vtB + c0 + (size_t)c * 1024 + 8 * g;
#pragma unroll
    for (int ht = 0; ht < 16; ++ht) {
      bf16x8 vf = *reinterpret_cast<const bf16x8*>(vb2 + (size_t)ht * 16384);
      acc[ht] = mfma16(paf, vf, acc[ht]);
    }
    __syncthreads();  // lK[bi] reads done; staging of lK[bi^1] drained
  }

  const float inv = 1.0f / l_run;
  float ia[4];
#pragma unroll
  for (int r = 0; r < 4; ++r) ia[r] = __shfl(inv, 4 * g + r);
#pragma unroll
  for (int ht = 0; ht < 16; ++ht) {
#pragma unroll
    for (int r = 0; r < 4; ++r) {
      size_t o = ((size_t)((b * 1024 + qbase + 4 * g + r) * 8 + n)) * 256 + ht * 16 + c;
      enc[o] = f2bf(acc[ht][r] * ia[r]);
    }
  }
}

extern "C" void kernel_launch(void* const* d_in, const int* in_sizes, int n_in,
                              void* d_out, int out_size, void* d_ws, size_t ws_size,
                              hipStream_t stream) {
  const float* x0 = (const float*)d_in[0];
  const float* x1 = (const float*)d_in[1];
  const float* wq0 = (const float*)d_in[2];
  const float* wkv0 = (const float*)d_in[3];
  const float* wo0 = (const float*)d_in[4];
  const float* wq1 = (const float*)d_in[5];
  const float* wkv1 = (const float*)d_in[6];
  const float* wo1 = (const float*)d_in[7];
  const int* pos = (const int*)d_in[8];
  float* out = (float*)d_out;

  float* out0 = out;                    // 4*768*2048
  float* out1 = out + 6291456;          // 4*256*1024
  float* k_out = out + 7340032;         // 4*1024*256
  float* v_out = out + 8388608;         // 4*1024*256

  char* ws = (char*)d_ws;
  size_t off = 0;
  auto alloc = [&](size_t bytes) {
    char* p = ws + off;
    off += (bytes + 255) & ~(size_t)255;
    return p;
  };
  US* x0b   = (US*)alloc(6291456ull * 2);
  US* x1b   = (US*)alloc(1048576ull * 2);
  US* btq0  = (US*)alloc(2048ull * 2048 * 2);   // btq0+btkv0 contiguous: [2560][2048]
  US* btkv0 = (US*)alloc(512ull * 2048 * 2);
  US* btq1  = (US*)alloc(2048ull * 1024 * 2);   // btq1+btkv1 contiguous: [2560][1024]
  US* btkv1 = (US*)alloc(512ull * 1024 * 2);
  US* bto0  = (US*)alloc(2048ull * 2048 * 2);
  US* bto1  = (US*)alloc(1024ull * 2048 * 2);
  float* q_raw  = (float*)alloc(8388608ull * 4);
  float* kv_raw = (float*)alloc(2097152ull * 4);
  US* q_bf = (US*)alloc(8388608ull * 2);
  US* k_bf = (US*)alloc(1048576ull * 2);
  US* vt   = (US*)alloc(1048576ull * 2 + 256);
  US* enc  = (US*)alloc(8388608ull * 2);
  (void)btkv0; (void)btkv1;

  // phase 1: casts + weight packs
  k_cast<<<6144, 256, 0, stream>>>(x0, x0b, 1572864);
  k_cast<<<1024, 256, 0, stream>>>(x1, x1b, 262144);
  k_tpack<<<dim3(8, 64, 8), dim3(32, 8), 0, stream>>>(wq0, btq0, 2048, 256, 2048L * 256, 256L * 2048);
  k_tpack<<<dim3(8, 64, 2), dim3(32, 8), 0, stream>>>(wkv0, btkv0, 2048, 256, 2048L * 256, 256L * 2048);
  k_tpack<<<dim3(8, 32, 8), dim3(32, 8), 0, stream>>>(wq1, btq1, 1024, 256, 1024L * 256, 256L * 1024);
  k_tpack<<<dim3(8, 32, 2), dim3(32, 8), 0, stream>>>(wkv1, btkv1, 1024, 256, 1024L * 256, 256L * 1024);
  k_tpack<<<dim3(64, 64, 1), dim3(32, 8), 0, stream>>>(wo0, bto0, 2048, 2048, 0, 0);
  k_tpack<<<dim3(32, 64, 1), dim3(32, 8), 0, stream>>>(wo1, bto1, 2048, 1024, 0, 0);

  // phase 2: fused QKV projection GEMMs (N=2560 = 2048 q + 512 kv)
  k_gemm_qkv<1><<<dim3(20, 24), 256, 0, stream>>>(x0b, btq0, q_raw, kv_raw, 3072, 2048);
  k_gemm_qkv<2><<<dim3(20, 8), 256, 0, stream>>>(x1b, btq1, q_raw, kv_raw, 1024, 1024);

  // phase 3: RoPE + V transpose (also emits k, v fp32 outputs)
  k_rope<<<4096, 256, 0, stream>>>(q_raw, kv_raw, pos, q_bf, k_bf, k_out);
  k_vtrans<<<dim3(32, 8, 4), dim3(32, 8), 0, stream>>>(kv_raw, v_out, vt);

  // phase 4: causal flash attention (2 heads/block, LPT drain, V via L2)
  k_attn<<<1024, 128, 0, stream>>>(q_bf, k_bf, vt, enc);

  // phase 5: fused output GEMMs
  k_gemm_out<<<dim3(16, 32), 256, 0, stream>>>(enc, bto0, bto1, out0, out1);
}

// Round 6
// 215.381 us; speedup vs baseline: 1.2293x; 1.2293x over previous
//
#include <hip/hip_runtime.h>
#include <hip/hip_bf16.h>

typedef __attribute__((ext_vector_type(8))) short bf16x8;
typedef __attribute__((ext_vector_type(4))) float f32x4;
typedef __attribute__((ext_vector_type(4))) unsigned short u16x4;
typedef unsigned short US;

__device__ __forceinline__ f32x4 mfma16(bf16x8 a, bf16x8 b, f32x4 c) {
  return __builtin_amdgcn_mfma_f32_16x16x32_bf16(a, b, c, 0, 0, 0);
}

__device__ __forceinline__ US f2bf(float f) {
  union { float f; unsigned u; } x; x.f = f;
  unsigned r = x.u + 0x7fffu + ((x.u >> 16) & 1u);
  return (US)(r >> 16);
}

// async global->LDS, 16B per lane; LDS dest = wave-uniform base + lane*16
__device__ __forceinline__ void gld16(const US* gp, US* lp) {
  __builtin_amdgcn_global_load_lds(
      (const __attribute__((address_space(1))) unsigned*)gp,
      (__attribute__((address_space(3))) unsigned*)lp, 16, 0, 0);
}

// RoPE column permutation: logical h (0..127) -> physical p; partner h+128 -> p+16.
// Guarantees pairs sit 16 apart in the same 64-col subtile (same thread, adjacent j).
__device__ __forceinline__ int permq(int h) {  // h in [0,128)
  return ((h >> 5) << 6) + (h & 15) + (((h >> 4) & 1) << 5);
}

// row remap fusing the time-concat: mode1: r=b*768+s -> b*1024+s ; mode2: r=b*256+s -> b*1024+768+s
__device__ __forceinline__ int map_row(int r, int mode) {
  if (mode == 1) { int b = r / 768; return b * 1024 + (r - b * 768); }
  if (mode == 2) { int b = r >> 8; return b * 1024 + 768 + (r & 255); }
  return r;
}

// ------- sin/cos table: sct[bt*128+j] = (sin, cos) of pos[bt]/ts(j) -------
__global__ __launch_bounds__(256)
void k_sincos(const int* __restrict__ pos, float2* __restrict__ sct) {
  int idx = blockIdx.x * 256 + threadIdx.x;   // 4096*128 entries
  int bt = idx >> 7, j = idx & 127;
  float inv_ts = powf(10000.0f, -(float)j * (1.0f / 128.0f));
  float r = (float)pos[bt] * inv_ts;
  sct[idx] = make_float2(sinf(r), cosf(r));
}

// ------- fused prep: casts + all 6 weight transpose-packs (q-packs h-permuted) -------
__global__ __launch_bounds__(256)
void k_prep(const float* __restrict__ x0, const float* __restrict__ x1,
            US* __restrict__ x0b, US* __restrict__ x1b,
            const float* __restrict__ wq0, const float* __restrict__ wkv0,
            const float* __restrict__ wq1, const float* __restrict__ wkv1,
            const float* __restrict__ wo0, const float* __restrict__ wo1,
            US* __restrict__ btq0, US* __restrict__ btkv0,
            US* __restrict__ btq1, US* __restrict__ btkv1,
            US* __restrict__ bto0, US* __restrict__ bto1) {
  const int bid = blockIdx.x;
  const int tid = threadIdx.x;
  if (bid < 7168) {  // bf16 casts
    const float* src; US* dst; int i;
    if (bid < 6144) { src = x0; dst = x0b; i = bid * 256 + tid; }
    else            { src = x1; dst = x1b; i = (bid - 6144) * 256 + tid; }
    f32x4 v = *reinterpret_cast<const f32x4*>(src + (size_t)i * 4);
    u16x4 o;
    o[0] = f2bf(v[0]); o[1] = f2bf(v[1]); o[2] = f2bf(v[2]); o[3] = f2bf(v[3]);
    *reinterpret_cast<u16x4*>(dst + (size_t)i * 4) = o;
    return;
  }
  __shared__ float tile[32][33];
  const float* src; US* dst; int R, C, CX, local; long sbs, dbs; bool pq = false;
  if (bid < 11264)      { local = bid - 7168;  src = wq0;  dst = btq0;  R = 2048; C = 256;  CX = 8;  sbs = 2048L * 256; dbs = 256L * 2048; pq = true; }
  else if (bid < 12288) { local = bid - 11264; src = wkv0; dst = btkv0; R = 2048; C = 256;  CX = 8;  sbs = 2048L * 256; dbs = 256L * 2048; }
  else if (bid < 14336) { local = bid - 12288; src = wq1;  dst = btq1;  R = 1024; C = 256;  CX = 8;  sbs = 1024L * 256; dbs = 256L * 1024; pq = true; }
  else if (bid < 14848) { local = bid - 14336; src = wkv1; dst = btkv1; R = 1024; C = 256;  CX = 8;  sbs = 1024L * 256; dbs = 256L * 1024; }
  else if (bid < 18944) { local = bid - 14848; src = wo0;  dst = bto0;  R = 2048; C = 2048; CX = 64; sbs = 0; dbs = 0; }
  else                  { local = bid - 18944; src = wo1;  dst = bto1;  R = 2048; C = 1024; CX = 32; sbs = 0; dbs = 0; }
  const int RY = R >> 5;
  const int cx = local % CX;
  const int rest = local / CX;
  const int ry = rest % RY;
  const int z = rest / RY;
  const int c0 = cx * 32, r0 = ry * 32;
  const int tx = tid & 31, ty = tid >> 5;
  src += (long)z * sbs;
  dst += (long)z * dbs;
#pragma unroll
  for (int i = 0; i < 4; ++i)
    tile[ty + 8 * i][tx] = src[(size_t)(r0 + ty + 8 * i) * C + c0 + tx];
  __syncthreads();
#pragma unroll
  for (int i = 0; i < 4; ++i) {
    int h = c0 + ty + 8 * i;
    int ph = pq ? ((h < 128) ? permq(h) : permq(h - 128) + 16) : h;
    dst[(size_t)ph * R + r0 + tx] = f2bf(tile[tx][ty + 8 * i]);
  }
}

// ------- fused QKV projection GEMM: A[M,K] x BT[2560,K]^T -------
// q columns: epilogue applies RoPE (permuted pairing) + scale, writes bf16 q_bf.
// kv columns: fp32 -> kv_raw. Double-buffered LDS, prefetch-before-compute.
template <int CMAP>
__global__ __launch_bounds__(256, 2)
void k_gemm_qkv(const US* __restrict__ A, const US* __restrict__ BT,
                US* __restrict__ q_bf, float* __restrict__ Ckv,
                const float2* __restrict__ sct, int M, int K) {
  __shared__ __align__(16) US lA[2][128 * 32];
  __shared__ __align__(16) US lB[2][128 * 32];
  const int tid = threadIdx.x;
  const int lane = tid & 63;
  const int wid = tid >> 6;
  const int wm = wid >> 1, wn = wid & 1;
  const int m0 = blockIdx.y * 128, n0 = blockIdx.x * 128;
  const int g = lane >> 4, c = lane & 15;
  const int lrow = lane >> 2, lcol = (lane & 3) * 8;
  const size_t ga0 = (size_t)(m0 + wid * 16 + lrow) * K + lcol;
  const size_t ga1 = (size_t)(m0 + 64 + wid * 16 + lrow) * K + lcol;
  const size_t gb0 = (size_t)(n0 + wid * 16 + lrow) * K + lcol;
  const size_t gb1 = (size_t)(n0 + 64 + wid * 16 + lrow) * K + lcol;

  auto stage = [&](int bi, int k0) {
    gld16(A + ga0 + k0, &lA[bi][(wid * 16) * 32]);
    gld16(A + ga1 + k0, &lA[bi][(64 + wid * 16) * 32]);
    gld16(BT + gb0 + k0, &lB[bi][(wid * 16) * 32]);
    gld16(BT + gb1 + k0, &lB[bi][(64 + wid * 16) * 32]);
  };

  f32x4 acc[4][4];
#pragma unroll
  for (int i = 0; i < 4; ++i)
#pragma unroll
    for (int j = 0; j < 4; ++j) acc[i][j] = f32x4{0.f, 0.f, 0.f, 0.f};

  const int nt = K >> 5;
  stage(0, 0);
  __syncthreads();
  for (int t = 0; t < nt; ++t) {
    const int bi = t & 1;
    if (t + 1 < nt) stage(bi ^ 1, (t + 1) * 32);
    bf16x8 af[4], bfr[4];
#pragma unroll
    for (int i = 0; i < 4; ++i) {
      af[i] = *reinterpret_cast<const bf16x8*>(&lA[bi][(wm * 64 + i * 16 + c) * 32 + g * 8]);
      bfr[i] = *reinterpret_cast<const bf16x8*>(&lB[bi][(wn * 64 + i * 16 + c) * 32 + g * 8]);
    }
#pragma unroll
    for (int i = 0; i < 4; ++i)
#pragma unroll
      for (int j = 0; j < 4; ++j)
        acc[i][j] = mfma16(af[i], bfr[j], acc[i][j]);
    __syncthreads();  // drains vmcnt(0): prefetch landed; buf[bi] reads done
  }

  const int colb = n0 + wn * 64;
  if (colb < 2048) {
    // q path: RoPE + scale -> bf16 (permuted layout; pairs are (j0,j1),(j2,j3))
    const int n = colb >> 8;
    const int base64 = colb & 255;
    const int h0 = (base64 >> 6) * 32 + c;
    const float scale = 0.0625f;
#pragma unroll
    for (int i = 0; i < 4; ++i) {
#pragma unroll
      for (int r = 0; r < 4; ++r) {
        const int orow = map_row(m0 + wm * 64 + i * 16 + 4 * g + r, CMAP);
        const float2 sc0 = sct[orow * 128 + h0];
        const float2 sc1 = sct[orow * 128 + h0 + 16];
        US* qp = q_bf + ((size_t)orow * 8 + n) * 256 + base64 + c;
        const float q1 = acc[i][0][r], q2 = acc[i][1][r];
        const float q3 = acc[i][2][r], q4 = acc[i][3][r];
        qp[0]  = f2bf(scale * (q1 * sc0.y - q2 * sc0.x));
        qp[16] = f2bf(scale * (q2 * sc0.y + q1 * sc0.x));
        qp[32] = f2bf(scale * (q3 * sc1.y - q4 * sc1.x));
        qp[48] = f2bf(scale * (q4 * sc1.y + q3 * sc1.x));
      }
    }
  } else {
    const int nb = colb - 2048 + c;
#pragma unroll
    for (int i = 0; i < 4; ++i) {
#pragma unroll
      for (int r = 0; r < 4; ++r) {
        const int orow = map_row(m0 + wm * 64 + i * 16 + 4 * g + r, CMAP);
        float* cp = Ckv + (size_t)orow * 512 + nb;
#pragma unroll
        for (int j = 0; j < 4; ++j) cp[j * 16] = acc[i][j][r];
      }
    }
  }
}

// ------- fused output GEMM: enc[4096,2048] -> out0 (rows s<768) / out1 (rows s>=768) -------
__global__ __launch_bounds__(256, 2)
void k_gemm_out(const US* __restrict__ A, const US* __restrict__ BT0, const US* __restrict__ BT1,
                float* __restrict__ C0, float* __restrict__ C1) {
  const int m0 = blockIdx.y * 128, n0 = blockIdx.x * 128;
  const int s0 = m0 & 1023;
  const bool is0 = (s0 < 768);
  if (!is0 && n0 >= 1024) return;
  const US* __restrict__ BT = is0 ? BT0 : BT1;
  const int K = 2048;
  __shared__ __align__(16) US lA[2][128 * 32];
  __shared__ __align__(16) US lB[2][128 * 32];
  const int tid = threadIdx.x;
  const int lane = tid & 63;
  const int wid = tid >> 6;
  const int wm = wid >> 1, wn = wid & 1;
  const int g = lane >> 4, c = lane & 15;
  const int lrow = lane >> 2, lcol = (lane & 3) * 8;
  const size_t ga0 = (size_t)(m0 + wid * 16 + lrow) * K + lcol;
  const size_t ga1 = (size_t)(m0 + 64 + wid * 16 + lrow) * K + lcol;
  const size_t gb0 = (size_t)(n0 + wid * 16 + lrow) * K + lcol;
  const size_t gb1 = (size_t)(n0 + 64 + wid * 16 + lrow) * K + lcol;

  auto stage = [&](int bi, int k0) {
    gld16(A + ga0 + k0, &lA[bi][(wid * 16) * 32]);
    gld16(A + ga1 + k0, &lA[bi][(64 + wid * 16) * 32]);
    gld16(BT + gb0 + k0, &lB[bi][(wid * 16) * 32]);
    gld16(BT + gb1 + k0, &lB[bi][(64 + wid * 16) * 32]);
  };

  f32x4 acc[4][4];
#pragma unroll
  for (int i = 0; i < 4; ++i)
#pragma unroll
    for (int j = 0; j < 4; ++j) acc[i][j] = f32x4{0.f, 0.f, 0.f, 0.f};

  const int nt = K >> 5;
  stage(0, 0);
  __syncthreads();
  for (int t = 0; t < nt; ++t) {
    const int bi = t & 1;
    if (t + 1 < nt) stage(bi ^ 1, (t + 1) * 32);
    bf16x8 af[4], bfr[4];
#pragma unroll
    for (int i = 0; i < 4; ++i) {
      af[i] = *reinterpret_cast<const bf16x8*>(&lA[bi][(wm * 64 + i * 16 + c) * 32 + g * 8]);
      bfr[i] = *reinterpret_cast<const bf16x8*>(&lB[bi][(wn * 64 + i * 16 + c) * 32 + g * 8]);
    }
#pragma unroll
    for (int i = 0; i < 4; ++i)
#pragma unroll
      for (int j = 0; j < 4; ++j)
        acc[i][j] = mfma16(af[i], bfr[j], acc[i][j]);
    __syncthreads();
  }

  const int col = n0 + wn * 64 + c;
#pragma unroll
  for (int i = 0; i < 4; ++i) {
#pragma unroll
    for (int r = 0; r < 4; ++r) {
      const int rf = m0 + wm * 64 + i * 16 + 4 * g + r;
      const int b = rf >> 10, s = rf & 1023;
      float* cp = is0 ? (C0 + (size_t)(b * 768 + s) * 2048 + col)
                      : (C1 + (size_t)(b * 256 + s - 768) * 1024 + col);
#pragma unroll
      for (int j = 0; j < 4; ++j) cp[j * 16] = acc[i][j][r];
    }
  }
}

// ------- k-RoPE: kv_raw k-part -> k_bf (permuted bf16) + k_out (logical fp32) -------
__global__ __launch_bounds__(128)
void k_ropek(const float* __restrict__ kv_raw, const float2* __restrict__ sct,
             US* __restrict__ k_bf, float* __restrict__ k_out) {
  const int bt = blockIdx.x;
  const int j = threadIdx.x;  // freq index 0..127
  const size_t ko = (size_t)bt * 512;
  const float x1 = kv_raw[ko + j], x2 = kv_raw[ko + j + 128];
  const float2 sc = sct[bt * 128 + j];
  const float o1 = x1 * sc.y - x2 * sc.x, o2 = x2 * sc.y + x1 * sc.x;
  const size_t kd = (size_t)bt * 256;
  const int p = permq(j);
  k_bf[kd + p] = f2bf(o1);
  k_bf[kd + p + 16] = f2bf(o2);
  k_out[kd + j] = o1;
  k_out[kd + j + 128] = o2;
}

// ------- V: kv_raw v-part -> v_out(f32) + vt bf16 [b][h][t] -------
__global__ __launch_bounds__(256)
void k_vtrans(const float* __restrict__ kv_raw, float* __restrict__ v_out, US* __restrict__ vt) {
  __shared__ float tile[32][33];
  int t0 = blockIdx.x * 32, h0 = blockIdx.y * 32, b = blockIdx.z;
  int tx = threadIdx.x, ty = threadIdx.y;
#pragma unroll
  for (int i = 0; i < 4; ++i) {
    int t = t0 + ty + 8 * i;
    float v = kv_raw[(size_t)(b * 1024 + t) * 512 + 256 + h0 + tx];
    tile[ty + 8 * i][tx] = v;
    v_out[(size_t)(b * 1024 + t) * 256 + h0 + tx] = v;
  }
  __syncthreads();
#pragma unroll
  for (int i = 0; i < 4; ++i) {
    int h = h0 + ty + 8 * i;
    vt[(size_t)(b * 256 + h) * 1024 + t0 + tx] = f2bf(tile[tx][ty + 8 * i]);
  }
}

// ------- flash attention: 512 blocks (qt x head-half x b), 4 waves = 4 heads -------
// (R4-verified structure: K+V LDS double-buffered, XOR-swizzled both-sides,
// work-rank pairing, defer-max). Added: s_setprio around MFMA clusters (T5).
__global__ __launch_bounds__(256, 2)
void k_attn(const US* __restrict__ qb, const US* __restrict__ kb,
            const US* __restrict__ vt, US* __restrict__ enc) {
  __shared__ __align__(16) US lK[2][32 * 256];   // 16KB x2
  __shared__ __align__(16) US lV[2][256 * 32];   // 16KB x2
  const int id = blockIdx.x;
  const int r0_ = (id < 256) ? id : 767 - id;    // work rank, descending length
  const int qt = 63 - (r0_ >> 3);
  const int hg = (r0_ >> 2) & 1;
  const int b = r0_ & 3;
  const int tid = threadIdx.x;
  const int wid = tid >> 6;
  const int lane = tid & 63;
  const int g = lane >> 4, c = lane & 15;
  const int qbase = qt * 16;
  const int n = hg * 4 + wid;

  const US* kbB = kb + (size_t)b * 262144;
  const US* vtB = vt + (size_t)b * 262144;

  bf16x8 qf[8];
  {
    const US* qp = qb + ((size_t)((b * 1024 + qbase + c) * 8 + n)) * 256 + 8 * g;
#pragma unroll
    for (int ch = 0; ch < 8; ++ch)
      qf[ch] = *reinterpret_cast<const bf16x8*>(qp + ch * 32);
  }

  // stage chunk [c0..c0+31]: K granule (r,s) holds global col-granule s^(r&7);
  // V granule (r,s) holds global col-granule s^((r>>1)&3). 4 waves cover the tiles.
  auto stage = [&](int bi, int c0) {
#pragma unroll
    for (int j = 0; j < 4; ++j) {
      const int rk = wid * 8 + j * 2 + (lane >> 5);
      const int sk = lane & 31;
      gld16(kbB + (size_t)(c0 + rk) * 256 + (sk ^ (rk & 7)) * 8,
            &lK[bi][(wid * 8 + j * 2) * 256]);
      const int rv = wid * 64 + j * 16 + (lane >> 2);
      const int sv = lane & 3;
      gld16(vtB + (size_t)rv * 1024 + c0 + (sv ^ ((rv >> 1) & 3)) * 8,
            &lV[bi][(wid * 64 + j * 16) * 32]);
    }
  };

  f32x4 acc[16];
#pragma unroll
  for (int i = 0; i < 16; ++i) acc[i] = f32x4{0.f, 0.f, 0.f, 0.f};
  float m_run = -3.0e38f, l_run = 0.f;

  const int nC = qbase / 32 + 1;
  stage(0, 0);
  __syncthreads();

  for (int i = 0; i < nC; ++i) {
    const int c0 = 32 * i;
    const int bi = i & 1;
    if (i + 1 < nC) stage(bi ^ 1, c0 + 32);

    const bool hb = (c0 + 16 <= qbase);
    f32x4 sA = {0.f, 0.f, 0.f, 0.f}, sB = {0.f, 0.f, 0.f, 0.f};
    __builtin_amdgcn_s_setprio(1);
#pragma unroll
    for (int ch = 0; ch < 8; ++ch) {
      const int slot = (((ch * 4 + g) ^ (c & 7)) * 8);
      sA = mfma16(*reinterpret_cast<const bf16x8*>(&lK[bi][c * 256 + slot]), qf[ch], sA);
    }
    if (hb) {
#pragma unroll
      for (int ch = 0; ch < 8; ++ch) {
        const int slot = (((ch * 4 + g) ^ (c & 7)) * 8);  // (c+16)&7 == c&7
        sB = mfma16(*reinterpret_cast<const bf16x8*>(&lK[bi][(c + 16) * 256 + slot]), qf[ch], sB);
      }
    }
    __builtin_amdgcn_s_setprio(0);
    if (c0 == qbase) {
#pragma unroll
      for (int r = 0; r < 4; ++r)
        if (4 * g + r > c) sA[r] = -3.0e38f;
    }
    if (hb && (c0 + 16 == qbase)) {
#pragma unroll
      for (int r = 0; r < 4; ++r)
        if (4 * g + r > c) sB[r] = -3.0e38f;
    }
    float tm = fmaxf(fmaxf(sA[0], sA[1]), fmaxf(sA[2], sA[3]));
    if (hb) tm = fmaxf(tm, fmaxf(fmaxf(sB[0], sB[1]), fmaxf(sB[2], sB[3])));
    tm = fmaxf(tm, __shfl_xor(tm, 16));
    tm = fmaxf(tm, __shfl_xor(tm, 32));
    // defer-max: only rescale when the running max actually grows past THR
    if (!__all(tm - m_run <= 8.0f)) {
      const float m_new = fmaxf(m_run, tm);
      const float alpha = __expf(m_run - m_new);
      float aacc[4];
#pragma unroll
      for (int r = 0; r < 4; ++r) aacc[r] = __shfl(alpha, 4 * g + r);
#pragma unroll
      for (int ht = 0; ht < 16; ++ht) {
        acc[ht][0] *= aacc[0]; acc[ht][1] *= aacc[1];
        acc[ht][2] *= aacc[2]; acc[ht][3] *= aacc[3];
      }
      l_run *= alpha;
      m_run = m_new;
    }
    float pA[4], pB[4];
    float ls = 0.f;
#pragma unroll
    for (int r = 0; r < 4; ++r) { pA[r] = __expf(sA[r] - m_run); ls += pA[r]; }
#pragma unroll
    for (int r = 0; r < 4; ++r) { pB[r] = hb ? __expf(sB[r] - m_run) : 0.f; ls += pB[r]; }
    ls += __shfl_xor(ls, 16);
    ls += __shfl_xor(ls, 32);
    l_run += ls;
    // redistribute P^T (D-layout) into PV A-fragment layout
    bf16x8 paf;
#pragma unroll
    for (int j = 0; j < 8; ++j) {
      const int srcl = ((2 * (g & 1) + (j >> 2)) << 4) + c;
      float va = __shfl(pA[j & 3], srcl);
      float vb = __shfl(pB[j & 3], srcl);
      float pv = (g < 2) ? va : vb;
      paf[j] = (short)f2bf(pv);
    }
    __builtin_amdgcn_s_setprio(1);
#pragma unroll
    for (int ht = 0; ht < 16; ++ht) {
      const int h = ht * 16 + c;
      const int slot = (g ^ ((c >> 1) & 3)) * 8;
      bf16x8 vf = *reinterpret_cast<const bf16x8*>(&lV[bi][h * 32 + slot]);
      acc[ht] = mfma16(paf, vf, acc[ht]);
    }
    __builtin_amdgcn_s_setprio(0);
    __syncthreads();  // buf[bi] reads done; staging of buf[bi^1] drained
  }

  const float inv = 1.0f / l_run;
  float ia[4];
#pragma unroll
  for (int r = 0; r < 4; ++r) ia[r] = __shfl(inv, 4 * g + r);
#pragma unroll
  for (int ht = 0; ht < 16; ++ht) {
#pragma unroll
    for (int r = 0; r < 4; ++r) {
      size_t o = ((size_t)((b * 1024 + qbase + 4 * g + r) * 8 + n)) * 256 + ht * 16 + c;
      enc[o] = f2bf(acc[ht][r] * ia[r]);
    }
  }
}

extern "C" void kernel_launch(void* const* d_in, const int* in_sizes, int n_in,
                              void* d_out, int out_size, void* d_ws, size_t ws_size,
                              hipStream_t stream) {
  const float* x0 = (const float*)d_in[0];
  const float* x1 = (const float*)d_in[1];
  const float* wq0 = (const float*)d_in[2];
  const float* wkv0 = (const float*)d_in[3];
  const float* wo0 = (const float*)d_in[4];
  const float* wq1 = (const float*)d_in[5];
  const float* wkv1 = (const float*)d_in[6];
  const float* wo1 = (const float*)d_in[7];
  const int* pos = (const int*)d_in[8];
  float* out = (float*)d_out;

  float* out0 = out;                    // 4*768*2048
  float* out1 = out + 6291456;          // 4*256*1024
  float* k_out = out + 7340032;         // 4*1024*256
  float* v_out = out + 8388608;         // 4*1024*256

  char* ws = (char*)d_ws;
  size_t off = 0;
  auto alloc = [&](size_t bytes) {
    char* p = ws + off;
    off += (bytes + 255) & ~(size_t)255;
    return p;
  };
  US* x0b   = (US*)alloc(6291456ull * 2);
  US* x1b   = (US*)alloc(1048576ull * 2);
  US* btq0  = (US*)alloc(2048ull * 2048 * 2);   // btq0+btkv0 contiguous: [2560][2048]
  US* btkv0 = (US*)alloc(512ull * 2048 * 2);
  US* btq1  = (US*)alloc(2048ull * 1024 * 2);   // btq1+btkv1 contiguous: [2560][1024]
  US* btkv1 = (US*)alloc(512ull * 1024 * 2);
  US* bto0  = (US*)alloc(2048ull * 2048 * 2);
  US* bto1  = (US*)alloc(1024ull * 2048 * 2);
  float* kv_raw = (float*)alloc(2097152ull * 4);
  US* q_bf = (US*)alloc(8388608ull * 2);
  US* k_bf = (US*)alloc(1048576ull * 2);
  US* vt   = (US*)alloc(1048576ull * 2 + 256);
  US* enc  = (US*)alloc(8388608ull * 2);
  float2* sct = (float2*)alloc(524288ull * 8);

  // phase 0: sin/cos table
  k_sincos<<<2048, 256, 0, stream>>>(pos, sct);

  // phase 1: fused casts + weight packs (q-weights h-permuted for epilogue RoPE)
  k_prep<<<20992, 256, 0, stream>>>(x0, x1, x0b, x1b, wq0, wkv0, wq1, wkv1, wo0, wo1,
                                    btq0, btkv0, btq1, btkv1, bto0, bto1);

  // phase 2: fused QKV projection GEMMs (q: RoPE fused in epilogue -> q_bf)
  k_gemm_qkv<1><<<dim3(20, 24), 256, 0, stream>>>(x0b, btq0, q_bf, kv_raw, sct, 3072, 2048);
  k_gemm_qkv<2><<<dim3(20, 8), 256, 0, stream>>>(x1b, btq1, q_bf, kv_raw, sct, 1024, 1024);

  // phase 3: k-RoPE + V transpose (emit k, v fp32 outputs)
  k_ropek<<<4096, 128, 0, stream>>>(kv_raw, sct, k_bf, k_out);
  k_vtrans<<<dim3(32, 8, 4), dim3(32, 8), 0, stream>>>(kv_raw, v_out, vt);

  // phase 4: causal flash attention (R4 structure + setprio)
  k_attn<<<512, 256, 0, stream>>>(q_bf, k_bf, vt, enc);

  // phase 5: fused output GEMMs
  k_gemm_out<<<dim3(16, 32), 256, 0, stream>>>(enc, bto0, bto1, out0, out1);
}

// Round 7
// 199.065 us; speedup vs baseline: 1.3301x; 1.0820x over previous
//
#include <hip/hip_runtime.h>
#include <hip/hip_bf16.h>

typedef __attribute__((ext_vector_type(8))) short bf16x8;
typedef __attribute__((ext_vector_type(4))) float f32x4;
typedef __attribute__((ext_vector_type(4))) unsigned short u16x4;
typedef unsigned short US;

__device__ __forceinline__ f32x4 mfma16(bf16x8 a, bf16x8 b, f32x4 c) {
  return __builtin_amdgcn_mfma_f32_16x16x32_bf16(a, b, c, 0, 0, 0);
}

__device__ __forceinline__ US f2bf(float f) {
  union { float f; unsigned u; } x; x.f = f;
  unsigned r = x.u + 0x7fffu + ((x.u >> 16) & 1u);
  return (US)(r >> 16);
}

// async global->LDS, 16B per lane; LDS dest = wave-uniform base + lane*16
__device__ __forceinline__ void gld16(const US* gp, US* lp) {
  __builtin_amdgcn_global_load_lds(
      (const __attribute__((address_space(1))) unsigned*)gp,
      (__attribute__((address_space(3))) unsigned*)lp, 16, 0, 0);
}

// RoPE column permutation: logical h (0..127) -> physical p; partner h+128 -> p+16.
__device__ __forceinline__ int permq(int h) {  // h in [0,128)
  return ((h >> 5) << 6) + (h & 15) + (((h >> 4) & 1) << 5);
}

// row remap fusing the time-concat: mode1: r=b*768+s -> b*1024+s ; mode2: r=b*256+s -> b*1024+768+s
__device__ __forceinline__ int map_row(int r, int mode) {
  if (mode == 1) { int b = r / 768; return b * 1024 + (r - b * 768); }
  if (mode == 2) { int b = r >> 8; return b * 1024 + 768 + (r & 255); }
  return r;
}

// ------- fused prep: casts + all 6 weight transpose-packs + sin/cos table -------
__global__ __launch_bounds__(256)
void k_prep(const float* __restrict__ x0, const float* __restrict__ x1,
            US* __restrict__ x0b, US* __restrict__ x1b,
            const float* __restrict__ wq0, const float* __restrict__ wkv0,
            const float* __restrict__ wq1, const float* __restrict__ wkv1,
            const float* __restrict__ wo0, const float* __restrict__ wo1,
            US* __restrict__ btq0, US* __restrict__ btkv0,
            US* __restrict__ btq1, US* __restrict__ btkv1,
            US* __restrict__ bto0, US* __restrict__ bto1,
            const int* __restrict__ pos, float2* __restrict__ sct) {
  const int bid = blockIdx.x;
  const int tid = threadIdx.x;
  if (bid >= 20992) {  // sin/cos table: 2048 blocks, 512K entries
    int idx = (bid - 20992) * 256 + tid;
    int bt = idx >> 7, j = idx & 127;
    float inv_ts = powf(10000.0f, -(float)j * (1.0f / 128.0f));
    float r = (float)pos[bt] * inv_ts;
    sct[idx] = make_float2(sinf(r), cosf(r));
    return;
  }
  if (bid < 7168) {  // bf16 casts
    const float* src; US* dst; int i;
    if (bid < 6144) { src = x0; dst = x0b; i = bid * 256 + tid; }
    else            { src = x1; dst = x1b; i = (bid - 6144) * 256 + tid; }
    f32x4 v = *reinterpret_cast<const f32x4*>(src + (size_t)i * 4);
    u16x4 o;
    o[0] = f2bf(v[0]); o[1] = f2bf(v[1]); o[2] = f2bf(v[2]); o[3] = f2bf(v[3]);
    *reinterpret_cast<u16x4*>(dst + (size_t)i * 4) = o;
    return;
  }
  __shared__ float tile[32][33];
  const float* src; US* dst; int R, C, CX, local; long sbs, dbs; bool pq = false;
  if (bid < 11264)      { local = bid - 7168;  src = wq0;  dst = btq0;  R = 2048; C = 256;  CX = 8;  sbs = 2048L * 256; dbs = 256L * 2048; pq = true; }
  else if (bid < 12288) { local = bid - 11264; src = wkv0; dst = btkv0; R = 2048; C = 256;  CX = 8;  sbs = 2048L * 256; dbs = 256L * 2048; }
  else if (bid < 14336) { local = bid - 12288; src = wq1;  dst = btq1;  R = 1024; C = 256;  CX = 8;  sbs = 1024L * 256; dbs = 256L * 1024; pq = true; }
  else if (bid < 14848) { local = bid - 14336; src = wkv1; dst = btkv1; R = 1024; C = 256;  CX = 8;  sbs = 1024L * 256; dbs = 256L * 1024; }
  else if (bid < 18944) { local = bid - 14848; src = wo0;  dst = bto0;  R = 2048; C = 2048; CX = 64; sbs = 0; dbs = 0; }
  else                  { local = bid - 18944; src = wo1;  dst = bto1;  R = 2048; C = 1024; CX = 32; sbs = 0; dbs = 0; }
  const int RY = R >> 5;
  const int cx = local % CX;
  const int rest = local / CX;
  const int ry = rest % RY;
  const int z = rest / RY;
  const int c0 = cx * 32, r0 = ry * 32;
  const int tx = tid & 31, ty = tid >> 5;
  src += (long)z * sbs;
  dst += (long)z * dbs;
#pragma unroll
  for (int i = 0; i < 4; ++i)
    tile[ty + 8 * i][tx] = src[(size_t)(r0 + ty + 8 * i) * C + c0 + tx];
  __syncthreads();
#pragma unroll
  for (int i = 0; i < 4; ++i) {
    int h = c0 + ty + 8 * i;
    int ph = pq ? ((h < 128) ? permq(h) : permq(h - 128) + 16) : h;
    dst[(size_t)ph * R + r0 + tx] = f2bf(tile[tx][ty + 8 * i]);
  }
}

// ------- merged QKV projection GEMM (both streams, one launch, XCD-swizzled) -------
// seg0 (480 blocks): x0b[3072,2048] x btq0[2560,2048]^T, cmap=1
// seg1 (160 blocks): x1b[1024,1024] x btq1[2560,1024]^T, cmap=2
// q columns: epilogue RoPE (permuted pairing) + scale -> bf16 q_bf; kv -> fp32 kv_raw.
__global__ __launch_bounds__(256, 2)
void k_gemm_qkv(const US* __restrict__ x0b, const US* __restrict__ x1b,
                const US* __restrict__ btq0, const US* __restrict__ btq1,
                US* __restrict__ q_bf, float* __restrict__ Ckv,
                const float2* __restrict__ sct) {
  const int bid = blockIdx.x;
  int id = (bid & 7) * 80 + (bid >> 3);   // bijective XCD swizzle (640 = 8*80)
  const US* A; const US* BT; int K, cmap, by, bx;
  if (id < 480) { A = x0b; BT = btq0; K = 2048; cmap = 1; by = id / 20; bx = id % 20; }
  else { id -= 480; A = x1b; BT = btq1; K = 1024; cmap = 2; by = id / 20; bx = id % 20; }

  __shared__ __align__(16) US lA[2][128 * 32];
  __shared__ __align__(16) US lB[2][128 * 32];
  const int tid = threadIdx.x;
  const int lane = tid & 63;
  const int wid = tid >> 6;
  const int wm = wid >> 1, wn = wid & 1;
  const int m0 = by * 128, n0 = bx * 128;
  const int g = lane >> 4, c = lane & 15;
  const int lrow = lane >> 2, lcol = (lane & 3) * 8;
  const size_t ga0 = (size_t)(m0 + wid * 16 + lrow) * K + lcol;
  const size_t ga1 = (size_t)(m0 + 64 + wid * 16 + lrow) * K + lcol;
  const size_t gb0 = (size_t)(n0 + wid * 16 + lrow) * K + lcol;
  const size_t gb1 = (size_t)(n0 + 64 + wid * 16 + lrow) * K + lcol;

  auto stage = [&](int bi, int k0) {
    gld16(A + ga0 + k0, &lA[bi][(wid * 16) * 32]);
    gld16(A + ga1 + k0, &lA[bi][(64 + wid * 16) * 32]);
    gld16(BT + gb0 + k0, &lB[bi][(wid * 16) * 32]);
    gld16(BT + gb1 + k0, &lB[bi][(64 + wid * 16) * 32]);
  };

  f32x4 acc[4][4];
#pragma unroll
  for (int i = 0; i < 4; ++i)
#pragma unroll
    for (int j = 0; j < 4; ++j) acc[i][j] = f32x4{0.f, 0.f, 0.f, 0.f};

  const int nt = K >> 5;
  stage(0, 0);
  __syncthreads();
  for (int t = 0; t < nt; ++t) {
    const int bi = t & 1;
    if (t + 1 < nt) stage(bi ^ 1, (t + 1) * 32);
    bf16x8 af[4], bfr[4];
#pragma unroll
    for (int i = 0; i < 4; ++i) {
      af[i] = *reinterpret_cast<const bf16x8*>(&lA[bi][(wm * 64 + i * 16 + c) * 32 + g * 8]);
      bfr[i] = *reinterpret_cast<const bf16x8*>(&lB[bi][(wn * 64 + i * 16 + c) * 32 + g * 8]);
    }
#pragma unroll
    for (int i = 0; i < 4; ++i)
#pragma unroll
      for (int j = 0; j < 4; ++j)
        acc[i][j] = mfma16(af[i], bfr[j], acc[i][j]);
    __syncthreads();  // drains vmcnt(0): prefetch landed; buf[bi] reads done
  }

  const int colb = n0 + wn * 64;
  if (colb < 2048) {
    // q path: RoPE + scale -> bf16 (permuted layout; pairs are (j0,j1),(j2,j3))
    const int n = colb >> 8;
    const int base64 = colb & 255;
    const int h0 = (base64 >> 6) * 32 + c;
    const float scale = 0.0625f;
#pragma unroll
    for (int i = 0; i < 4; ++i) {
#pragma unroll
      for (int r = 0; r < 4; ++r) {
        const int orow = map_row(m0 + wm * 64 + i * 16 + 4 * g + r, cmap);
        const float2 sc0 = sct[orow * 128 + h0];
        const float2 sc1 = sct[orow * 128 + h0 + 16];
        US* qp = q_bf + ((size_t)orow * 8 + n) * 256 + base64 + c;
        const float q1 = acc[i][0][r], q2 = acc[i][1][r];
        const float q3 = acc[i][2][r], q4 = acc[i][3][r];
        qp[0]  = f2bf(scale * (q1 * sc0.y - q2 * sc0.x));
        qp[16] = f2bf(scale * (q2 * sc0.y + q1 * sc0.x));
        qp[32] = f2bf(scale * (q3 * sc1.y - q4 * sc1.x));
        qp[48] = f2bf(scale * (q4 * sc1.y + q3 * sc1.x));
      }
    }
  } else {
    const int nb = colb - 2048 + c;
#pragma unroll
    for (int i = 0; i < 4; ++i) {
#pragma unroll
      for (int r = 0; r < 4; ++r) {
        const int orow = map_row(m0 + wm * 64 + i * 16 + 4 * g + r, cmap);
        float* cp = Ckv + (size_t)orow * 512 + nb;
#pragma unroll
        for (int j = 0; j < 4; ++j) cp[j * 16] = acc[i][j][r];
      }
    }
  }
}

// ------- compact output GEMM: 448 tiles (384 out0 + 64 out1), XCD-swizzled -------
__global__ __launch_bounds__(256, 2)
void k_gemm_out(const US* __restrict__ A, const US* __restrict__ BT0, const US* __restrict__ BT1,
                float* __restrict__ C0, float* __restrict__ C1) {
  const int bid = blockIdx.x;
  int id = (bid & 7) * 56 + (bid >> 3);   // bijective XCD swizzle (448 = 8*56)
  const US* BT; float* Cb; int amap, mt, ntile, Nst;
  if (id < 384) { amap = 1; mt = id / 16; ntile = id % 16; BT = BT0; Cb = C0; Nst = 2048; }
  else { id -= 384; amap = 2; mt = id / 8; ntile = id % 8; BT = BT1; Cb = C1; Nst = 1024; }
  const int m0 = mt * 128, n0 = ntile * 128;
  const int K = 2048;
  __shared__ __align__(16) US lA[2][128 * 32];
  __shared__ __align__(16) US lB[2][128 * 32];
  const int tid = threadIdx.x;
  const int lane = tid & 63;
  const int wid = tid >> 6;
  const int wm = wid >> 1, wn = wid & 1;
  const int g = lane >> 4, c = lane & 15;
  const int lrow = lane >> 2, lcol = (lane & 3) * 8;
  const size_t ga0 = (size_t)map_row(m0 + wid * 16 + lrow, amap) * K + lcol;
  const size_t ga1 = (size_t)map_row(m0 + 64 + wid * 16 + lrow, amap) * K + lcol;
  const size_t gb0 = (size_t)(n0 + wid * 16 + lrow) * K + lcol;
  const size_t gb1 = (size_t)(n0 + 64 + wid * 16 + lrow) * K + lcol;

  auto stage = [&](int bi, int k0) {
    gld16(A + ga0 + k0, &lA[bi][(wid * 16) * 32]);
    gld16(A + ga1 + k0, &lA[bi][(64 + wid * 16) * 32]);
    gld16(BT + gb0 + k0, &lB[bi][(wid * 16) * 32]);
    gld16(BT + gb1 + k0, &lB[bi][(64 + wid * 16) * 32]);
  };

  f32x4 acc[4][4];
#pragma unroll
  for (int i = 0; i < 4; ++i)
#pragma unroll
    for (int j = 0; j < 4; ++j) acc[i][j] = f32x4{0.f, 0.f, 0.f, 0.f};

  const int nt = K >> 5;
  stage(0, 0);
  __syncthreads();
  for (int t = 0; t < nt; ++t) {
    const int bi = t & 1;
    if (t + 1 < nt) stage(bi ^ 1, (t + 1) * 32);
    bf16x8 af[4], bfr[4];
#pragma unroll
    for (int i = 0; i < 4; ++i) {
      af[i] = *reinterpret_cast<const bf16x8*>(&lA[bi][(wm * 64 + i * 16 + c) * 32 + g * 8]);
      bfr[i] = *reinterpret_cast<const bf16x8*>(&lB[bi][(wn * 64 + i * 16 + c) * 32 + g * 8]);
    }
#pragma unroll
    for (int i = 0; i < 4; ++i)
#pragma unroll
      for (int j = 0; j < 4; ++j)
        acc[i][j] = mfma16(af[i], bfr[j], acc[i][j]);
    __syncthreads();
  }

  const int col = n0 + wn * 64 + c;
#pragma unroll
  for (int i = 0; i < 4; ++i) {
#pragma unroll
    for (int r = 0; r < 4; ++r) {
      const int orow = m0 + wm * 64 + i * 16 + 4 * g + r;  // compact per-segment row
      float* cp = Cb + (size_t)orow * Nst + col;
#pragma unroll
      for (int j = 0; j < 4; ++j) cp[j * 16] = acc[i][j][r];
    }
  }
}

// ------- merged post-KV: V transpose (+v_out) and k-RoPE (+k_out) in one launch -------
__global__ __launch_bounds__(256)
void k_postkv(const float* __restrict__ kv_raw, const float2* __restrict__ sct,
              US* __restrict__ k_bf, float* __restrict__ k_out,
              float* __restrict__ v_out, US* __restrict__ vt) {
  const int bid = blockIdx.x;
  const int tid = threadIdx.x;
  if (bid >= 1024) {  // k-RoPE: 2048 blocks, 2 bt-rows each
    const int bt = (bid - 1024) * 2 + (tid >> 7);
    const int j = tid & 127;
    const size_t ko = (size_t)bt * 512;
    const float x1 = kv_raw[ko + j], x2 = kv_raw[ko + j + 128];
    const float2 sc = sct[bt * 128 + j];
    const float o1 = x1 * sc.y - x2 * sc.x, o2 = x2 * sc.y + x1 * sc.x;
    const size_t kd = (size_t)bt * 256;
    const int p = permq(j);
    k_bf[kd + p] = f2bf(o1);
    k_bf[kd + p + 16] = f2bf(o2);
    k_out[kd + j] = o1;
    k_out[kd + j + 128] = o2;
    return;
  }
  __shared__ float tile[32][33];
  const int t0 = (bid & 31) * 32, h0 = ((bid >> 5) & 7) * 32, b = bid >> 8;
  const int tx = tid & 31, ty = tid >> 5;
#pragma unroll
  for (int i = 0; i < 4; ++i) {
    int t = t0 + ty + 8 * i;
    float v = kv_raw[(size_t)(b * 1024 + t) * 512 + 256 + h0 + tx];
    tile[ty + 8 * i][tx] = v;
    v_out[(size_t)(b * 1024 + t) * 256 + h0 + tx] = v;
  }
  __syncthreads();
#pragma unroll
  for (int i = 0; i < 4; ++i) {
    int h = h0 + ty + 8 * i;
    vt[(size_t)(b * 256 + h) * 1024 + t0 + tx] = f2bf(tile[tx][ty + 8 * i]);
  }
}

// ------- flash attention: 512 blocks (qt x head-half x b), 4 waves = 4 heads -------
// (R4-verified structure: K+V LDS double-buffered, XOR-swizzled both-sides,
// work-rank pairing, defer-max, setprio around MFMA clusters.)
__global__ __launch_bounds__(256, 2)
void k_attn(const US* __restrict__ qb, const US* __restrict__ kb,
            const US* __restrict__ vt, US* __restrict__ enc) {
  __shared__ __align__(16) US lK[2][32 * 256];   // 16KB x2
  __shared__ __align__(16) US lV[2][256 * 32];   // 16KB x2
  const int id = blockIdx.x;
  const int r0_ = (id < 256) ? id : 767 - id;    // work rank, descending length
  const int qt = 63 - (r0_ >> 3);
  const int hg = (r0_ >> 2) & 1;
  const int b = r0_ & 3;
  const int tid = threadIdx.x;
  const int wid = tid >> 6;
  const int lane = tid & 63;
  const int g = lane >> 4, c = lane & 15;
  const int qbase = qt * 16;
  const int n = hg * 4 + wid;

  const US* kbB = kb + (size_t)b * 262144;
  const US* vtB = vt + (size_t)b * 262144;

  bf16x8 qf[8];
  {
    const US* qp = qb + ((size_t)((b * 1024 + qbase + c) * 8 + n)) * 256 + 8 * g;
#pragma unroll
    for (int ch = 0; ch < 8; ++ch)
      qf[ch] = *reinterpret_cast<const bf16x8*>(qp + ch * 32);
  }

  auto stage = [&](int bi, int c0) {
#pragma unroll
    for (int j = 0; j < 4; ++j) {
      const int rk = wid * 8 + j * 2 + (lane >> 5);
      const int sk = lane & 31;
      gld16(kbB + (size_t)(c0 + rk) * 256 + (sk ^ (rk & 7)) * 8,
            &lK[bi][(wid * 8 + j * 2) * 256]);
      const int rv = wid * 64 + j * 16 + (lane >> 2);
      const int sv = lane & 3;
      gld16(vtB + (size_t)rv * 1024 + c0 + (sv ^ ((rv >> 1) & 3)) * 8,
            &lV[bi][(wid * 64 + j * 16) * 32]);
    }
  };

  f32x4 acc[16];
#pragma unroll
  for (int i = 0; i < 16; ++i) acc[i] = f32x4{0.f, 0.f, 0.f, 0.f};
  float m_run = -3.0e38f, l_run = 0.f;

  const int nC = qbase / 32 + 1;
  stage(0, 0);
  __syncthreads();

  for (int i = 0; i < nC; ++i) {
    const int c0 = 32 * i;
    const int bi = i & 1;
    if (i + 1 < nC) stage(bi ^ 1, c0 + 32);

    const bool hb = (c0 + 16 <= qbase);
    f32x4 sA = {0.f, 0.f, 0.f, 0.f}, sB = {0.f, 0.f, 0.f, 0.f};
    __builtin_amdgcn_s_setprio(1);
#pragma unroll
    for (int ch = 0; ch < 8; ++ch) {
      const int slot = (((ch * 4 + g) ^ (c & 7)) * 8);
      sA = mfma16(*reinterpret_cast<const bf16x8*>(&lK[bi][c * 256 + slot]), qf[ch], sA);
    }
    if (hb) {
#pragma unroll
      for (int ch = 0; ch < 8; ++ch) {
        const int slot = (((ch * 4 + g) ^ (c & 7)) * 8);  // (c+16)&7 == c&7
        sB = mfma16(*reinterpret_cast<const bf16x8*>(&lK[bi][(c + 16) * 256 + slot]), qf[ch], sB);
      }
    }
    __builtin_amdgcn_s_setprio(0);
    if (c0 == qbase) {
#pragma unroll
      for (int r = 0; r < 4; ++r)
        if (4 * g + r > c) sA[r] = -3.0e38f;
    }
    if (hb && (c0 + 16 == qbase)) {
#pragma unroll
      for (int r = 0; r < 4; ++r)
        if (4 * g + r > c) sB[r] = -3.0e38f;
    }
    float tm = fmaxf(fmaxf(sA[0], sA[1]), fmaxf(sA[2], sA[3]));
    if (hb) tm = fmaxf(tm, fmaxf(fmaxf(sB[0], sB[1]), fmaxf(sB[2], sB[3])));
    tm = fmaxf(tm, __shfl_xor(tm, 16));
    tm = fmaxf(tm, __shfl_xor(tm, 32));
    // defer-max: only rescale when the running max actually grows past THR
    if (!__all(tm - m_run <= 8.0f)) {
      const float m_new = fmaxf(m_run, tm);
      const float alpha = __expf(m_run - m_new);
      float aacc[4];
#pragma unroll
      for (int r = 0; r < 4; ++r) aacc[r] = __shfl(alpha, 4 * g + r);
#pragma unroll
      for (int ht = 0; ht < 16; ++ht) {
        acc[ht][0] *= aacc[0]; acc[ht][1] *= aacc[1];
        acc[ht][2] *= aacc[2]; acc[ht][3] *= aacc[3];
      }
      l_run *= alpha;
      m_run = m_new;
    }
    float pA[4], pB[4];
    float ls = 0.f;
#pragma unroll
    for (int r = 0; r < 4; ++r) { pA[r] = __expf(sA[r] - m_run); ls += pA[r]; }
#pragma unroll
    for (int r = 0; r < 4; ++r) { pB[r] = hb ? __expf(sB[r] - m_run) : 0.f; ls += pB[r]; }
    ls += __shfl_xor(ls, 16);
    ls += __shfl_xor(ls, 32);
    l_run += ls;
    // redistribute P^T (D-layout) into PV A-fragment layout
    bf16x8 paf;
#pragma unroll
    for (int j = 0; j < 8; ++j) {
      const int srcl = ((2 * (g & 1) + (j >> 2)) << 4) + c;
      float va = __shfl(pA[j & 3], srcl);
      float vb = __shfl(pB[j & 3], srcl);
      float pv = (g < 2) ? va : vb;
      paf[j] = (short)f2bf(pv);
    }
    __builtin_amdgcn_s_setprio(1);
#pragma unroll
    for (int ht = 0; ht < 16; ++ht) {
      const int h = ht * 16 + c;
      const int slot = (g ^ ((c >> 1) & 3)) * 8;
      bf16x8 vf = *reinterpret_cast<const bf16x8*>(&lV[bi][h * 32 + slot]);
      acc[ht] = mfma16(paf, vf, acc[ht]);
    }
    __builtin_amdgcn_s_setprio(0);
    __syncthreads();  // buf[bi] reads done; staging of buf[bi^1] drained
  }

  const float inv = 1.0f / l_run;
  float ia[4];
#pragma unroll
  for (int r = 0; r < 4; ++r) ia[r] = __shfl(inv, 4 * g + r);
#pragma unroll
  for (int ht = 0; ht < 16; ++ht) {
#pragma unroll
    for (int r = 0; r < 4; ++r) {
      size_t o = ((size_t)((b * 1024 + qbase + 4 * g + r) * 8 + n)) * 256 + ht * 16 + c;
      enc[o] = f2bf(acc[ht][r] * ia[r]);
    }
  }
}

extern "C" void kernel_launch(void* const* d_in, const int* in_sizes, int n_in,
                              void* d_out, int out_size, void* d_ws, size_t ws_size,
                              hipStream_t stream) {
  const float* x0 = (const float*)d_in[0];
  const float* x1 = (const float*)d_in[1];
  const float* wq0 = (const float*)d_in[2];
  const float* wkv0 = (const float*)d_in[3];
  const float* wo0 = (const float*)d_in[4];
  const float* wq1 = (const float*)d_in[5];
  const float* wkv1 = (const float*)d_in[6];
  const float* wo1 = (const float*)d_in[7];
  const int* pos = (const int*)d_in[8];
  float* out = (float*)d_out;

  float* out0 = out;                    // 4*768*2048
  float* out1 = out + 6291456;          // 4*256*1024
  float* k_out = out + 7340032;         // 4*1024*256
  float* v_out = out + 8388608;         // 4*1024*256

  char* ws = (char*)d_ws;
  size_t off = 0;
  auto alloc = [&](size_t bytes) {
    char* p = ws + off;
    off += (bytes + 255) & ~(size_t)255;
    return p;
  };
  US* x0b   = (US*)alloc(6291456ull * 2);
  US* x1b   = (US*)alloc(1048576ull * 2);
  US* btq0  = (US*)alloc(2048ull * 2048 * 2);   // btq0+btkv0 contiguous: [2560][2048]
  US* btkv0 = (US*)alloc(512ull * 2048 * 2);
  US* btq1  = (US*)alloc(2048ull * 1024 * 2);   // btq1+btkv1 contiguous: [2560][1024]
  US* btkv1 = (US*)alloc(512ull * 1024 * 2);
  US* bto0  = (US*)alloc(2048ull * 2048 * 2);
  US* bto1  = (US*)alloc(1024ull * 2048 * 2);
  float* kv_raw = (float*)alloc(2097152ull * 4);
  US* q_bf = (US*)alloc(8388608ull * 2);
  US* k_bf = (US*)alloc(1048576ull * 2);
  US* vt   = (US*)alloc(1048576ull * 2 + 256);
  US* enc  = (US*)alloc(8388608ull * 2);
  float2* sct = (float2*)alloc(524288ull * 8);
  (void)btkv0; (void)btkv1;

  // phase 1: fused casts + weight packs + sin/cos table
  k_prep<<<23040, 256, 0, stream>>>(x0, x1, x0b, x1b, wq0, wkv0, wq1, wkv1, wo0, wo1,
                                    btq0, btkv0, btq1, btkv1, bto0, bto1, pos, sct);

  // phase 2: merged QKV projection GEMMs (both streams, RoPE-q fused epilogue)
  k_gemm_qkv<<<640, 256, 0, stream>>>(x0b, x1b, btq0, btq1, q_bf, kv_raw, sct);

  // phase 3: merged k-RoPE + V transpose (emit k, v fp32 outputs)
  k_postkv<<<3072, 256, 0, stream>>>(kv_raw, sct, k_bf, k_out, v_out, vt);

  // phase 4: causal flash attention
  k_attn<<<512, 256, 0, stream>>>(q_bf, k_bf, vt, enc);

  // phase 5: compact fused output GEMM (448 tiles, no holes)
  k_gemm_out<<<448, 256, 0, stream>>>(enc, bto0, bto1, out0, out1);
}

// Round 8
// 194.525 us; speedup vs baseline: 1.3611x; 1.0233x over previous
//
#include <hip/hip_runtime.h>
#include <hip/hip_bf16.h>

typedef __attribute__((ext_vector_type(8))) short bf16x8;
typedef __attribute__((ext_vector_type(4))) float f32x4;
typedef __attribute__((ext_vector_type(4))) unsigned short u16x4;
typedef unsigned short US;

__device__ __forceinline__ f32x4 mfma16(bf16x8 a, bf16x8 b, f32x4 c) {
  return __builtin_amdgcn_mfma_f32_16x16x32_bf16(a, b, c, 0, 0, 0);
}

__device__ __forceinline__ US f2bf(float f) {
  union { float f; unsigned u; } x; x.f = f;
  unsigned r = x.u + 0x7fffu + ((x.u >> 16) & 1u);
  return (US)(r >> 16);
}

// async global->LDS, 16B per lane; LDS dest = wave-uniform base + lane*16
__device__ __forceinline__ void gld16(const US* gp, US* lp) {
  __builtin_amdgcn_global_load_lds(
      (const __attribute__((address_space(1))) unsigned*)gp,
      (__attribute__((address_space(3))) unsigned*)lp, 16, 0, 0);
}

// RoPE column permutation: logical h (0..127) -> physical p; partner h+128 -> p+16.
__device__ __forceinline__ int permq(int h) {  // h in [0,128)
  return ((h >> 5) << 6) + (h & 15) + (((h >> 4) & 1) << 5);
}

// row remap fusing the time-concat: mode1: r=b*768+s -> b*1024+s ; mode2: r=b*256+s -> b*1024+768+s
__device__ __forceinline__ int map_row(int r, int mode) {
  if (mode == 1) { int b = r / 768; return b * 1024 + (r - b * 768); }
  if (mode == 2) { int b = r >> 8; return b * 1024 + 768 + (r & 255); }
  return r;
}

// ------- fused prep: casts + all 6 weight transpose-packs + sin/cos table -------
__global__ __launch_bounds__(256)
void k_prep(const float* __restrict__ x0, const float* __restrict__ x1,
            US* __restrict__ x0b, US* __restrict__ x1b,
            const float* __restrict__ wq0, const float* __restrict__ wkv0,
            const float* __restrict__ wq1, const float* __restrict__ wkv1,
            const float* __restrict__ wo0, const float* __restrict__ wo1,
            US* __restrict__ btq0, US* __restrict__ btkv0,
            US* __restrict__ btq1, US* __restrict__ btkv1,
            US* __restrict__ bto0, US* __restrict__ bto1,
            const int* __restrict__ pos, float2* __restrict__ sct) {
  const int bid = blockIdx.x;
  const int tid = threadIdx.x;
  if (bid >= 20992) {  // sin/cos table: 2048 blocks, 512K entries
    int idx = (bid - 20992) * 256 + tid;
    int bt = idx >> 7, j = idx & 127;
    float inv_ts = powf(10000.0f, -(float)j * (1.0f / 128.0f));
    float r = (float)pos[bt] * inv_ts;
    sct[idx] = make_float2(sinf(r), cosf(r));
    return;
  }
  if (bid < 7168) {  // bf16 casts
    const float* src; US* dst; int i;
    if (bid < 6144) { src = x0; dst = x0b; i = bid * 256 + tid; }
    else            { src = x1; dst = x1b; i = (bid - 6144) * 256 + tid; }
    f32x4 v = *reinterpret_cast<const f32x4*>(src + (size_t)i * 4);
    u16x4 o;
    o[0] = f2bf(v[0]); o[1] = f2bf(v[1]); o[2] = f2bf(v[2]); o[3] = f2bf(v[3]);
    *reinterpret_cast<u16x4*>(dst + (size_t)i * 4) = o;
    return;
  }
  __shared__ float tile[32][33];
  const float* src; US* dst; int R, C, CX, local; long sbs, dbs; bool pq = false;
  if (bid < 11264)      { local = bid - 7168;  src = wq0;  dst = btq0;  R = 2048; C = 256;  CX = 8;  sbs = 2048L * 256; dbs = 256L * 2048; pq = true; }
  else if (bid < 12288) { local = bid - 11264; src = wkv0; dst = btkv0; R = 2048; C = 256;  CX = 8;  sbs = 2048L * 256; dbs = 256L * 2048; }
  else if (bid < 14336) { local = bid - 12288; src = wq1;  dst = btq1;  R = 1024; C = 256;  CX = 8;  sbs = 1024L * 256; dbs = 256L * 1024; pq = true; }
  else if (bid < 14848) { local = bid - 14336; src = wkv1; dst = btkv1; R = 1024; C = 256;  CX = 8;  sbs = 1024L * 256; dbs = 256L * 1024; }
  else if (bid < 18944) { local = bid - 14848; src = wo0;  dst = bto0;  R = 2048; C = 2048; CX = 64; sbs = 0; dbs = 0; }
  else                  { local = bid - 18944; src = wo1;  dst = bto1;  R = 2048; C = 1024; CX = 32; sbs = 0; dbs = 0; }
  const int RY = R >> 5;
  const int cx = local % CX;
  const int rest = local / CX;
  const int ry = rest % RY;
  const int z = rest / RY;
  const int c0 = cx * 32, r0 = ry * 32;
  const int tx = tid & 31, ty = tid >> 5;
  src += (long)z * sbs;
  dst += (long)z * dbs;
#pragma unroll
  for (int i = 0; i < 4; ++i)
    tile[ty + 8 * i][tx] = src[(size_t)(r0 + ty + 8 * i) * C + c0 + tx];
  __syncthreads();
#pragma unroll
  for (int i = 0; i < 4; ++i) {
    int h = c0 + ty + 8 * i;
    int ph = pq ? ((h < 128) ? permq(h) : permq(h - 128) + 16) : h;
    dst[(size_t)ph * R + r0 + tx] = f2bf(tile[tx][ty + 8 * i]);
  }
}

// ------- merged QKV projection GEMM (both streams, one launch, XCD-swizzled) -------
__global__ __launch_bounds__(256, 2)
void k_gemm_qkv(const US* __restrict__ x0b, const US* __restrict__ x1b,
                const US* __restrict__ btq0, const US* __restrict__ btq1,
                US* __restrict__ q_bf, float* __restrict__ Ckv,
                const float2* __restrict__ sct) {
  const int bid = blockIdx.x;
  int id = (bid & 7) * 80 + (bid >> 3);   // bijective XCD swizzle (640 = 8*80)
  const US* A; const US* BT; int K, cmap, by, bx;
  if (id < 480) { A = x0b; BT = btq0; K = 2048; cmap = 1; by = id / 20; bx = id % 20; }
  else { id -= 480; A = x1b; BT = btq1; K = 1024; cmap = 2; by = id / 20; bx = id % 20; }

  __shared__ __align__(16) US lA[2][128 * 32];
  __shared__ __align__(16) US lB[2][128 * 32];
  const int tid = threadIdx.x;
  const int lane = tid & 63;
  const int wid = tid >> 6;
  const int wm = wid >> 1, wn = wid & 1;
  const int m0 = by * 128, n0 = bx * 128;
  const int g = lane >> 4, c = lane & 15;
  const int lrow = lane >> 2, lcol = (lane & 3) * 8;
  const size_t ga0 = (size_t)(m0 + wid * 16 + lrow) * K + lcol;
  const size_t ga1 = (size_t)(m0 + 64 + wid * 16 + lrow) * K + lcol;
  const size_t gb0 = (size_t)(n0 + wid * 16 + lrow) * K + lcol;
  const size_t gb1 = (size_t)(n0 + 64 + wid * 16 + lrow) * K + lcol;

  auto stage = [&](int bi, int k0) {
    gld16(A + ga0 + k0, &lA[bi][(wid * 16) * 32]);
    gld16(A + ga1 + k0, &lA[bi][(64 + wid * 16) * 32]);
    gld16(BT + gb0 + k0, &lB[bi][(wid * 16) * 32]);
    gld16(BT + gb1 + k0, &lB[bi][(64 + wid * 16) * 32]);
  };

  f32x4 acc[4][4];
#pragma unroll
  for (int i = 0; i < 4; ++i)
#pragma unroll
    for (int j = 0; j < 4; ++j) acc[i][j] = f32x4{0.f, 0.f, 0.f, 0.f};

  const int nt = K >> 5;
  stage(0, 0);
  __syncthreads();
  for (int t = 0; t < nt; ++t) {
    const int bi = t & 1;
    if (t + 1 < nt) stage(bi ^ 1, (t + 1) * 32);
    bf16x8 af[4], bfr[4];
#pragma unroll
    for (int i = 0; i < 4; ++i) {
      af[i] = *reinterpret_cast<const bf16x8*>(&lA[bi][(wm * 64 + i * 16 + c) * 32 + g * 8]);
      bfr[i] = *reinterpret_cast<const bf16x8*>(&lB[bi][(wn * 64 + i * 16 + c) * 32 + g * 8]);
    }
#pragma unroll
    for (int i = 0; i < 4; ++i)
#pragma unroll
      for (int j = 0; j < 4; ++j)
        acc[i][j] = mfma16(af[i], bfr[j], acc[i][j]);
    __syncthreads();  // drains vmcnt(0): prefetch landed; buf[bi] reads done
  }

  const int colb = n0 + wn * 64;
  if (colb < 2048) {
    // q path: RoPE + scale -> bf16 (permuted layout; pairs are (j0,j1),(j2,j3))
    const int n = colb >> 8;
    const int base64 = colb & 255;
    const int h0 = (base64 >> 6) * 32 + c;
    const float scale = 0.0625f;
#pragma unroll
    for (int i = 0; i < 4; ++i) {
#pragma unroll
      for (int r = 0; r < 4; ++r) {
        const int orow = map_row(m0 + wm * 64 + i * 16 + 4 * g + r, cmap);
        const float2 sc0 = sct[orow * 128 + h0];
        const float2 sc1 = sct[orow * 128 + h0 + 16];
        US* qp = q_bf + ((size_t)orow * 8 + n) * 256 + base64 + c;
        const float q1 = acc[i][0][r], q2 = acc[i][1][r];
        const float q3 = acc[i][2][r], q4 = acc[i][3][r];
        qp[0]  = f2bf(scale * (q1 * sc0.y - q2 * sc0.x));
        qp[16] = f2bf(scale * (q2 * sc0.y + q1 * sc0.x));
        qp[32] = f2bf(scale * (q3 * sc1.y - q4 * sc1.x));
        qp[48] = f2bf(scale * (q4 * sc1.y + q3 * sc1.x));
      }
    }
  } else {
    const int nb = colb - 2048 + c;
#pragma unroll
    for (int i = 0; i < 4; ++i) {
#pragma unroll
      for (int r = 0; r < 4; ++r) {
        const int orow = map_row(m0 + wm * 64 + i * 16 + 4 * g + r, cmap);
        float* cp = Ckv + (size_t)orow * 512 + nb;
#pragma unroll
        for (int j = 0; j < 4; ++j) cp[j * 16] = acc[i][j][r];
      }
    }
  }
}

// ------- compact output GEMM: 448 tiles (384 out0 + 64 out1), XCD-swizzled -------
__global__ __launch_bounds__(256, 2)
void k_gemm_out(const US* __restrict__ A, const US* __restrict__ BT0, const US* __restrict__ BT1,
                float* __restrict__ C0, float* __restrict__ C1) {
  const int bid = blockIdx.x;
  int id = (bid & 7) * 56 + (bid >> 3);   // bijective XCD swizzle (448 = 8*56)
  const US* BT; float* Cb; int amap, mt, ntile, Nst;
  if (id < 384) { amap = 1; mt = id / 16; ntile = id % 16; BT = BT0; Cb = C0; Nst = 2048; }
  else { id -= 384; amap = 2; mt = id / 8; ntile = id % 8; BT = BT1; Cb = C1; Nst = 1024; }
  const int m0 = mt * 128, n0 = ntile * 128;
  const int K = 2048;
  __shared__ __align__(16) US lA[2][128 * 32];
  __shared__ __align__(16) US lB[2][128 * 32];
  const int tid = threadIdx.x;
  const int lane = tid & 63;
  const int wid = tid >> 6;
  const int wm = wid >> 1, wn = wid & 1;
  const int g = lane >> 4, c = lane & 15;
  const int lrow = lane >> 2, lcol = (lane & 3) * 8;
  const size_t ga0 = (size_t)map_row(m0 + wid * 16 + lrow, amap) * K + lcol;
  const size_t ga1 = (size_t)map_row(m0 + 64 + wid * 16 + lrow, amap) * K + lcol;
  const size_t gb0 = (size_t)(n0 + wid * 16 + lrow) * K + lcol;
  const size_t gb1 = (size_t)(n0 + 64 + wid * 16 + lrow) * K + lcol;

  auto stage = [&](int bi, int k0) {
    gld16(A + ga0 + k0, &lA[bi][(wid * 16) * 32]);
    gld16(A + ga1 + k0, &lA[bi][(64 + wid * 16) * 32]);
    gld16(BT + gb0 + k0, &lB[bi][(wid * 16) * 32]);
    gld16(BT + gb1 + k0, &lB[bi][(64 + wid * 16) * 32]);
  };

  f32x4 acc[4][4];
#pragma unroll
  for (int i = 0; i < 4; ++i)
#pragma unroll
    for (int j = 0; j < 4; ++j) acc[i][j] = f32x4{0.f, 0.f, 0.f, 0.f};

  const int nt = K >> 5;
  stage(0, 0);
  __syncthreads();
  for (int t = 0; t < nt; ++t) {
    const int bi = t & 1;
    if (t + 1 < nt) stage(bi ^ 1, (t + 1) * 32);
    bf16x8 af[4], bfr[4];
#pragma unroll
    for (int i = 0; i < 4; ++i) {
      af[i] = *reinterpret_cast<const bf16x8*>(&lA[bi][(wm * 64 + i * 16 + c) * 32 + g * 8]);
      bfr[i] = *reinterpret_cast<const bf16x8*>(&lB[bi][(wn * 64 + i * 16 + c) * 32 + g * 8]);
    }
#pragma unroll
    for (int i = 0; i < 4; ++i)
#pragma unroll
      for (int j = 0; j < 4; ++j)
        acc[i][j] = mfma16(af[i], bfr[j], acc[i][j]);
    __syncthreads();
  }

  const int col = n0 + wn * 64 + c;
#pragma unroll
  for (int i = 0; i < 4; ++i) {
#pragma unroll
    for (int r = 0; r < 4; ++r) {
      const int orow = m0 + wm * 64 + i * 16 + 4 * g + r;  // compact per-segment row
      float* cp = Cb + (size_t)orow * Nst + col;
#pragma unroll
      for (int j = 0; j < 4; ++j) cp[j * 16] = acc[i][j][r];
    }
  }
}

// ------- merged post-KV: V transpose (+v_out) and k-RoPE (+k_out) in one launch -------
__global__ __launch_bounds__(256)
void k_postkv(const float* __restrict__ kv_raw, const float2* __restrict__ sct,
              US* __restrict__ k_bf, float* __restrict__ k_out,
              float* __restrict__ v_out, US* __restrict__ vt) {
  const int bid = blockIdx.x;
  const int tid = threadIdx.x;
  if (bid >= 1024) {  // k-RoPE: 2048 blocks, 2 bt-rows each
    const int bt = (bid - 1024) * 2 + (tid >> 7);
    const int j = tid & 127;
    const size_t ko = (size_t)bt * 512;
    const float x1 = kv_raw[ko + j], x2 = kv_raw[ko + j + 128];
    const float2 sc = sct[bt * 128 + j];
    const float o1 = x1 * sc.y - x2 * sc.x, o2 = x2 * sc.y + x1 * sc.x;
    const size_t kd = (size_t)bt * 256;
    const int p = permq(j);
    k_bf[kd + p] = f2bf(o1);
    k_bf[kd + p + 16] = f2bf(o2);
    k_out[kd + j] = o1;
    k_out[kd + j + 128] = o2;
    return;
  }
  __shared__ float tile[32][33];
  const int t0 = (bid & 31) * 32, h0 = ((bid >> 5) & 7) * 32, b = bid >> 8;
  const int tx = tid & 31, ty = tid >> 5;
#pragma unroll
  for (int i = 0; i < 4; ++i) {
    int t = t0 + ty + 8 * i;
    float v = kv_raw[(size_t)(b * 1024 + t) * 512 + 256 + h0 + tx];
    tile[ty + 8 * i][tx] = v;
    v_out[(size_t)(b * 1024 + t) * 256 + h0 + tx] = v;
  }
  __syncthreads();
#pragma unroll
  for (int i = 0; i < 4; ++i) {
    int h = h0 + ty + 8 * i;
    vt[(size_t)(b * 256 + h) * 1024 + t0 + tx] = f2bf(tile[tx][ty + 8 * i]);
  }
}

// ------- flash attention: 512 blocks (qt x head-half x b), 4 waves = 4 heads -------
// R4 structure + T12-style paf butterfly: 4 cvt_pk + 4 shfl replace 16 shfl + 8 f2bf.
__global__ __launch_bounds__(256, 2)
void k_attn(const US* __restrict__ qb, const US* __restrict__ kb,
            const US* __restrict__ vt, US* __restrict__ enc) {
  __shared__ __align__(16) US lK[2][32 * 256];   // 16KB x2
  __shared__ __align__(16) US lV[2][256 * 32];   // 16KB x2
  const int id = blockIdx.x;
  const int r0_ = (id < 256) ? id : 767 - id;    // work rank, descending length
  const int qt = 63 - (r0_ >> 3);
  const int hg = (r0_ >> 2) & 1;
  const int b = r0_ & 3;
  const int tid = threadIdx.x;
  const int wid = tid >> 6;
  const int lane = tid & 63;
  const int g = lane >> 4, c = lane & 15;
  const int qbase = qt * 16;
  const int n = hg * 4 + wid;

  const US* kbB = kb + (size_t)b * 262144;
  const US* vtB = vt + (size_t)b * 262144;

  bf16x8 qf[8];
  {
    const US* qp = qb + ((size_t)((b * 1024 + qbase + c) * 8 + n)) * 256 + 8 * g;
#pragma unroll
    for (int ch = 0; ch < 8; ++ch)
      qf[ch] = *reinterpret_cast<const bf16x8*>(qp + ch * 32);
  }

  auto stage = [&](int bi, int c0) {
#pragma unroll
    for (int j = 0; j < 4; ++j) {
      const int rk = wid * 8 + j * 2 + (lane >> 5);
      const int sk = lane & 31;
      gld16(kbB + (size_t)(c0 + rk) * 256 + (sk ^ (rk & 7)) * 8,
            &lK[bi][(wid * 8 + j * 2) * 256]);
      const int rv = wid * 64 + j * 16 + (lane >> 2);
      const int sv = lane & 3;
      gld16(vtB + (size_t)rv * 1024 + c0 + (sv ^ ((rv >> 1) & 3)) * 8,
            &lV[bi][(wid * 64 + j * 16) * 32]);
    }
  };

  f32x4 acc[16];
#pragma unroll
  for (int i = 0; i < 16; ++i) acc[i] = f32x4{0.f, 0.f, 0.f, 0.f};
  float m_run = -3.0e38f, l_run = 0.f;

  const int nC = qbase / 32 + 1;
  stage(0, 0);
  __syncthreads();

  for (int i = 0; i < nC; ++i) {
    const int c0 = 32 * i;
    const int bi = i & 1;
    if (i + 1 < nC) stage(bi ^ 1, c0 + 32);

    const bool hb = (c0 + 16 <= qbase);
    f32x4 sA = {0.f, 0.f, 0.f, 0.f}, sB = {0.f, 0.f, 0.f, 0.f};
    __builtin_amdgcn_s_setprio(1);
#pragma unroll
    for (int ch = 0; ch < 8; ++ch) {
      const int slot = (((ch * 4 + g) ^ (c & 7)) * 8);
      sA = mfma16(*reinterpret_cast<const bf16x8*>(&lK[bi][c * 256 + slot]), qf[ch], sA);
    }
    if (hb) {
#pragma unroll
      for (int ch = 0; ch < 8; ++ch) {
        const int slot = (((ch * 4 + g) ^ (c & 7)) * 8);  // (c+16)&7 == c&7
        sB = mfma16(*reinterpret_cast<const bf16x8*>(&lK[bi][(c + 16) * 256 + slot]), qf[ch], sB);
      }
    }
    __builtin_amdgcn_s_setprio(0);
    if (c0 == qbase) {
#pragma unroll
      for (int r = 0; r < 4; ++r)
        if (4 * g + r > c) sA[r] = -3.0e38f;
    }
    if (hb && (c0 + 16 == qbase)) {
#pragma unroll
      for (int r = 0; r < 4; ++r)
        if (4 * g + r > c) sB[r] = -3.0e38f;
    }
    float tm = fmaxf(fmaxf(sA[0], sA[1]), fmaxf(sA[2], sA[3]));
    if (hb) tm = fmaxf(tm, fmaxf(fmaxf(sB[0], sB[1]), fmaxf(sB[2], sB[3])));
    tm = fmaxf(tm, __shfl_xor(tm, 16));
    tm = fmaxf(tm, __shfl_xor(tm, 32));
    // defer-max: only rescale when the running max actually grows past THR
    if (!__all(tm - m_run <= 8.0f)) {
      const float m_new = fmaxf(m_run, tm);
      const float alpha = __expf(m_run - m_new);
      float aacc[4];
#pragma unroll
      for (int r = 0; r < 4; ++r) aacc[r] = __shfl(alpha, 4 * g + r);
#pragma unroll
      for (int ht = 0; ht < 16; ++ht) {
        acc[ht][0] *= aacc[0]; acc[ht][1] *= aacc[1];
        acc[ht][2] *= aacc[2]; acc[ht][3] *= aacc[3];
      }
      l_run *= alpha;
      m_run = m_new;
    }
    float pA[4], pB[4];
    float ls = 0.f;
#pragma unroll
    for (int r = 0; r < 4; ++r) { pA[r] = __expf(sA[r] - m_run); ls += pA[r]; }
#pragma unroll
    for (int r = 0; r < 4; ++r) { pB[r] = hb ? __expf(sB[r] - m_run) : 0.f; ls += pB[r]; }
    ls += __shfl_xor(ls, 16);
    ls += __shfl_xor(ls, 32);
    l_run += ls;

    // --- paf butterfly: pack P to bf16 pairs, then 2-stage 4-lane-group transpose ---
    // source lane (g',c): w0=kv(4g',4g'+1) w1=kv(4g'+2,+3) [pA]; w2,w3 same for kv+16 [pB].
    // target lane (g,c) needs u32s t0..t3 = kv(8g..8g+7) pairs.
    unsigned w0, w1, w2, w3;
    asm("v_cvt_pk_bf16_f32 %0, %1, %2" : "=v"(w0) : "v"(pA[0]), "v"(pA[1]));
    asm("v_cvt_pk_bf16_f32 %0, %1, %2" : "=v"(w1) : "v"(pA[2]), "v"(pA[3]));
    asm("v_cvt_pk_bf16_f32 %0, %1, %2" : "=v"(w2) : "v"(pB[0]), "v"(pB[1]));
    asm("v_cvt_pk_bf16_f32 %0, %1, %2" : "=v"(w3) : "v"(pB[2]), "v"(pB[3]));
    const bool bb1 = ((g >> 1) & 1) != 0, bb0 = (g & 1) != 0;
    // stage 1 (^32): keep own pair=b1 words, send pair=!b1; receive partner's pair=b1
    unsigned ownA = bb1 ? w2 : w0, ownB = bb1 ? w3 : w1;
    unsigned sndA = bb1 ? w0 : w2, sndB = bb1 ? w1 : w3;
    unsigned rcvA = (unsigned)__shfl_xor((int)sndA, 32);
    unsigned rcvB = (unsigned)__shfl_xor((int)sndB, 32);
    // stage 2 (^16): keep entry with src-hi==b0 (own has hi=b1, rcv has hi=!b1)
    unsigned kA = (bb0 == bb1) ? ownA : rcvA, kB = (bb0 == bb1) ? ownB : rcvB;
    unsigned s2A = (bb0 == bb1) ? rcvA : ownA, s2B = (bb0 == bb1) ? rcvB : ownB;
    unsigned gA = (unsigned)__shfl_xor((int)s2A, 16);
    unsigned gB = (unsigned)__shfl_xor((int)s2B, 16);
    // order by src-lo: kept has lo=b0, got has lo=!b0
    union { unsigned u[4]; bf16x8 v; } pu;
    pu.u[0] = bb0 ? gA : kA; pu.u[1] = bb0 ? gB : kB;
    pu.u[2] = bb0 ? kA : gA; pu.u[3] = bb0 ? kB : gB;
    const bf16x8 paf = pu.v;

    __builtin_amdgcn_s_setprio(1);
#pragma unroll
    for (int ht = 0; ht < 16; ++ht) {
      const int h = ht * 16 + c;
      const int slot = (g ^ ((c >> 1) & 3)) * 8;
      bf16x8 vf = *reinterpret_cast<const bf16x8*>(&lV[bi][h * 32 + slot]);
      acc[ht] = mfma16(paf, vf, acc[ht]);
    }
    __builtin_amdgcn_s_setprio(0);
    __syncthreads();  // buf[bi] reads done; staging of buf[bi^1] drained
  }

  const float inv = 1.0f / l_run;
  float ia[4];
#pragma unroll
  for (int r = 0; r < 4; ++r) ia[r] = __shfl(inv, 4 * g + r);
#pragma unroll
  for (int ht = 0; ht < 16; ++ht) {
#pragma unroll
    for (int r = 0; r < 4; ++r) {
      size_t o = ((size_t)((b * 1024 + qbase + 4 * g + r) * 8 + n)) * 256 + ht * 16 + c;
      enc[o] = f2bf(acc[ht][r] * ia[r]);
    }
  }
}

extern "C" void kernel_launch(void* const* d_in, const int* in_sizes, int n_in,
                              void* d_out, int out_size, void* d_ws, size_t ws_size,
                              hipStream_t stream) {
  const float* x0 = (const float*)d_in[0];
  const float* x1 = (const float*)d_in[1];
  const float* wq0 = (const float*)d_in[2];
  const float* wkv0 = (const float*)d_in[3];
  const float* wo0 = (const float*)d_in[4];
  const float* wq1 = (const float*)d_in[5];
  const float* wkv1 = (const float*)d_in[6];
  const float* wo1 = (const float*)d_in[7];
  const int* pos = (const int*)d_in[8];
  float* out = (float*)d_out;

  float* out0 = out;                    // 4*768*2048
  float* out1 = out + 6291456;          // 4*256*1024
  float* k_out = out + 7340032;         // 4*1024*256
  float* v_out = out + 8388608;         // 4*1024*256

  char* ws = (char*)d_ws;
  size_t off = 0;
  auto alloc = [&](size_t bytes) {
    char* p = ws + off;
    off += (bytes + 255) & ~(size_t)255;
    return p;
  };
  US* x0b   = (US*)alloc(6291456ull * 2);
  US* x1b   = (US*)alloc(1048576ull * 2);
  US* btq0  = (US*)alloc(2048ull * 2048 * 2);   // btq0+btkv0 contiguous: [2560][2048]
  US* btkv0 = (US*)alloc(512ull * 2048 * 2);
  US* btq1  = (US*)alloc(2048ull * 1024 * 2);   // btq1+btkv1 contiguous: [2560][1024]
  US* btkv1 = (US*)alloc(512ull * 1024 * 2);
  US* bto0  = (US*)alloc(2048ull * 2048 * 2);
  US* bto1  = (US*)alloc(1024ull * 2048 * 2);
  float* kv_raw = (float*)alloc(2097152ull * 4);
  US* q_bf = (US*)alloc(8388608ull * 2);
  US* k_bf = (US*)alloc(1048576ull * 2);
  US* vt   = (US*)alloc(1048576ull * 2 + 256);
  US* enc  = (US*)alloc(8388608ull * 2);
  float2* sct = (float2*)alloc(524288ull * 8);
  (void)btkv0; (void)btkv1;

  // phase 1: fused casts + weight packs + sin/cos table
  k_prep<<<23040, 256, 0, stream>>>(x0, x1, x0b, x1b, wq0, wkv0, wq1, wkv1, wo0, wo1,
                                    btq0, btkv0, btq1, btkv1, bto0, bto1, pos, sct);

  // phase 2: merged QKV projection GEMMs (both streams, RoPE-q fused epilogue)
  k_gemm_qkv<<<640, 256, 0, stream>>>(x0b, x1b, btq0, btq1, q_bf, kv_raw, sct);

  // phase 3: merged k-RoPE + V transpose (emit k, v fp32 outputs)
  k_postkv<<<3072, 256, 0, stream>>>(kv_raw, sct, k_bf, k_out, v_out, vt);

  // phase 4: causal flash attention (paf butterfly)
  k_attn<<<512, 256, 0, stream>>>(q_bf, k_bf, vt, enc);

  // phase 5: compact fused output GEMM (448 tiles, no holes)
  k_gemm_out<<<448, 256, 0, stream>>>(enc, bto0, bto1, out0, out1);
}